// Round 4
// baseline (280.687 us; speedup 1.0000x reference)
//
#include <hip/hip_runtime.h>
#include <hip/hip_bf16.h>

// G2AAgent — ROUND 12: launch diet II (8 -> 5 dispatches), kSeq untouched.
//  R11 post-mortem: kSeq conflict prediction MISSED (5.44M, up not down) yet
//  time improved — conflicts ~9us of 121, not binding. kSeq is at a
//  structural plateau (VALU 55 + MFMA 19 + LDS + 15 barriers). The bigger
//  lever: 159us of 280 is OUTSIDE kSeq across 7 dispatches whose compute
//  sums to ~40us — R2->R3 showed ~8us per dispatch boundary. This round:
//   (a) kDetect -> absorbed into kConvert (per-block self-detect, L2-hot);
//   (b) kGemm(x1)+kGemm(gi_c) -> kFused12 (x1 swapped-MFMA -> per-wave LDS
//       tile, same-wave readback, no barrier; kills 8.4MB x1 round-trip);
//   (c) kAttn+kGemmOut -> kTail (agg staged in LDS, out-GEMM reads LDS
//       A-frags; kills 8.4MB agg round-trip).
//  All arithmetic order preserved -> bit-identical output expected.

typedef __attribute__((ext_vector_type(8))) short short8;
typedef __attribute__((ext_vector_type(4))) short short4v;
typedef __attribute__((ext_vector_type(4))) float float4v;
typedef __attribute__((ext_vector_type(2))) unsigned long long ull2;

#define BF2F(x) __bfloat162float(x)
typedef __hip_bfloat16 bf;

__device__ __forceinline__ float frcp(float x) {
  return __builtin_amdgcn_rcpf(x);
}
__device__ __forceinline__ float fsigmoid(float x) {
  return frcp(1.f + __expf(-x));
}
__device__ __forceinline__ float ftanh(float x) {
  float e = __expf(2.f * x);
  return 1.f - 2.f * frcp(1.f + e);
}
__device__ __forceinline__ float rdv(const void* p, int i, int f) {
  return f ? ((const float*)p)[i] : BF2F(((const bf*)p)[i]);
}
__device__ __forceinline__ float upk(unsigned long long v, int s) {
  union { unsigned int i; float f; } x;
  x.i = ((unsigned int)((v >> s) & 0xffffULL)) << 16;
  return x.f;
}

// ---------------------------------------------------------------------------
static const int AO[23] = {
  0, 2097152, 4194304, 4685824, 4702208, 4702336, 4751488, 4800640, 4801024,
  4801408, 4899712, 4948864, 4949248, 4949632, 5047936, 5097088, 5097472,
  5097856, 5098368, 5098384, 5102480, 5106576, 5110160};
static const int AN[23] = {
  2097152, 2097152, 491520, 16384, 128, 49152, 49152, 384, 384, 98304, 49152,
  384, 384, 98304, 49152, 384, 384, 512, 2, 4096, 4096, 3584, 14};

struct CArgs {
  const void* src[23];
  int n[23];
  int off[23];
};

// ---------------------------------------------------------------------------
// kConvert: per-block self-detect of input dtype (scans first 4096 u16 of
// d_in[0], L2-hot); y<23 = vectorized normalize into arena (skips 2/18/22);
// y==23 = prep (Wqk/W2p/Wcb). Block (0,0) publishes flag for kTail.
__global__ void kConvert(CArgs a, int* __restrict__ flagOut,
                         bf* __restrict__ arena,
                         const void* __restrict__ WqR, const void* __restrict__ WkR,
                         const void* __restrict__ W2R, const void* __restrict__ WcR,
                         bf* __restrict__ Wqk, bf* __restrict__ W2p,
                         bf* __restrict__ Wcb) {
  __shared__ int sflag;
  if (threadIdx.x == 0) sflag = 0;
  __syncthreads();
  {
    const unsigned short* p0 = (const unsigned short*)a.src[0];
    int hit = 0;
    for (int i = threadIdx.x; i < 4096; i += 256) {
      int e = (p0[i] >> 7) & 0xFF;
      if (e >= 0xC0) hit = 1;
    }
    if (hit) atomicOr(&sflag, 1);
  }
  __syncthreads();
  const int f = sflag;
  const int b = blockIdx.y;
  if (b == 0 && blockIdx.x == 0 && threadIdx.x == 0) *flagOut = f;

  if (b == 23) {  // prep
    int idx = blockIdx.x * 256 + threadIdx.x;
    if (idx < 8192) {
      int r = idx >> 7, c = idx & 127;
      float v = (r < 32) ? rdv(WqR, r * 128 + c, f) : rdv(WkR, (r - 32) * 128 + c, f);
      Wqk[idx] = __float2bfloat16(v);
    }
    if (idx < 4096)
      W2p[idx] = __float2bfloat16((idx < 3584) ? rdv(W2R, idx, f) : 0.f);
    if (idx < 512) {
      int dir = idx >> 8, l = (idx >> 7) & 1, k = idx & 127;
      Wcb[idx] = __float2bfloat16(rdv(WcR, l * 256 + dir * 128 + k, f));
    }
    return;
  }
  if (b == 2 || b == 18 || b == 22) return;  // consumed raw via rdv
  const int n = a.n[b];
  const int nv = n & ~7;
  bf* dst = arena + a.off[b];
  const int gid = blockIdx.x * 256 + threadIdx.x;
  const int gs = gridDim.x * 256;
  if (f) {
    const float* s = (const float*)a.src[b];
    for (int i = gid * 8; i < nv; i += gs * 8) {
      float4 x0 = *(const float4*)(s + i);
      float4 x1 = *(const float4*)(s + i + 4);
      short8 v;
      bf t;
      t = __float2bfloat16(x0.x); v[0] = *(short*)&t;
      t = __float2bfloat16(x0.y); v[1] = *(short*)&t;
      t = __float2bfloat16(x0.z); v[2] = *(short*)&t;
      t = __float2bfloat16(x0.w); v[3] = *(short*)&t;
      t = __float2bfloat16(x1.x); v[4] = *(short*)&t;
      t = __float2bfloat16(x1.y); v[5] = *(short*)&t;
      t = __float2bfloat16(x1.z); v[6] = *(short*)&t;
      t = __float2bfloat16(x1.w); v[7] = *(short*)&t;
      *(short8*)(dst + i) = v;
    }
    for (int i = nv + gid; i < n; i += gs) dst[i] = __float2bfloat16(s[i]);
  } else {
    const short8* s = (const short8*)a.src[b];
    short8* d = (short8*)dst;
    for (int i = gid; i * 8 < nv; i += gs) d[i] = s[i];
    const unsigned short* ss = (const unsigned short*)a.src[b];
    unsigned short* ds = (unsigned short*)dst;
    for (int i = nv + gid; i < n; i += gs) ds[i] = ss[i];
  }
}

// ---------------------------------------------------------------------------
// kFused12: x1 = relu(inputs[64xIN] @ W1^T + b1) per block (64 rows), staged
// per-wave in LDS (swapped MFMA -> b64 stores, same-wave readback, no
// barrier), then gi_c[64x384] = x1 @ Wih_c^T streamed in 64-col groups.
__global__ __launch_bounds__(256) void kFused12(
    const bf* __restrict__ inputs, const bf* __restrict__ W1,
    const bf* __restrict__ b1, const bf* __restrict__ Wih,
    const bf* __restrict__ bih, bf* __restrict__ gi) {
  __shared__ bf sX[4][16][136];  // per-wave x1 tile, 17.4 KB
  const int tid = threadIdx.x;
  const int wave = tid >> 6, lane = tid & 63;
  const int quad = lane >> 4, ci = lane & 15;
  const int row0 = blockIdx.x * 64 + wave * 16;

  // stage A: swapped -> D[x1col][row]; thread owns cols ct*16+quad*4+{0..3},
  // row row0+ci.
  float4v xa[8];
#pragma unroll
  for (int i = 0; i < 8; ++i) xa[i] = {0.f, 0.f, 0.f, 0.f};
#pragma unroll
  for (int ks = 0; ks < 4; ++ks) {
    short8 inr = *(const short8*)(inputs + (size_t)(row0 + ci) * 128 + ks * 32 + quad * 8);
#pragma unroll
    for (int ct = 0; ct < 8; ++ct) {
      short8 wfr = *(const short8*)(W1 + (size_t)(ct * 16 + ci) * 128 + ks * 32 + quad * 8);
      xa[ct] = __builtin_amdgcn_mfma_f32_16x16x32_bf16(wfr, inr, xa[ct], 0, 0, 0);
    }
  }
#pragma unroll
  for (int ct = 0; ct < 8; ++ct) {
    short4v v4;
#pragma unroll
    for (int r = 0; r < 4; ++r) {
      float v = xa[ct][r] + BF2F(b1[ct * 16 + quad * 4 + r]);
      v = fmaxf(v, 0.f);
      bf t = __float2bfloat16(v);
      v4[r] = *(short*)&t;
    }
    *(short4v*)&sX[wave][ci][ct * 16 + quad * 4] = v4;
  }
  // same-wave readback (lgkmcnt-ordered, no barrier needed)
  short8 af[4];
#pragma unroll
  for (int ks = 0; ks < 4; ++ks)
    af[ks] = *(const short8*)&sX[wave][ci][ks * 32 + quad * 8];

  // stage B: gi (standard D[row][col]), 6 col-groups of 64
  for (int cg = 0; cg < 6; ++cg) {
    float4v acc[4];
#pragma unroll
    for (int i = 0; i < 4; ++i) acc[i] = {0.f, 0.f, 0.f, 0.f};
#pragma unroll
    for (int ks = 0; ks < 4; ++ks)
#pragma unroll
      for (int nt = 0; nt < 4; ++nt) {
        short8 b = *(const short8*)(Wih + (size_t)(cg * 64 + nt * 16 + ci) * 128 + ks * 32 + quad * 8);
        acc[nt] = __builtin_amdgcn_mfma_f32_16x16x32_bf16(af[ks], b, acc[nt], 0, 0, 0);
      }
#pragma unroll
    for (int nt = 0; nt < 4; ++nt) {
      int col = cg * 64 + nt * 16 + ci;
      float bv = BF2F(bih[col]);
#pragma unroll
      for (int r = 0; r < 4; ++r)
        gi[(size_t)(row0 + quad * 4 + r) * 384 + col] = __float2bfloat16(acc[nt][r] + bv);
    }
  }
}

// ---------------------------------------------------------------------------
// kStep: single GRU step (cell GRU only).
__global__ __launch_bounds__(256, 4) void kStep(
    const bf* __restrict__ Hp, const bf* __restrict__ Whh,
    const bf* __restrict__ G, int gld,
    const bf* __restrict__ bhh,
    bf* __restrict__ Ho, float* __restrict__ HcopyF) {
  const int half = blockIdx.z;
  const int tid = threadIdx.x;
  const int wave = tid >> 6, lane = tid & 63;
  const int quad = lane >> 4, ci = lane & 15;
  const int mr = blockIdx.x * 64 + wave * 16;

  float4v acc[12];
#pragma unroll
  for (int i = 0; i < 12; ++i) acc[i] = {0.f, 0.f, 0.f, 0.f};

#pragma unroll
  for (int ks = 0; ks < 4; ++ks) {
    short8 a = *(const short8*)(Hp + (size_t)(mr + ci) * 128 + ks * 32 + quad * 8);
#pragma unroll
    for (int g = 0; g < 3; ++g)
#pragma unroll
      for (int nt = 0; nt < 4; ++nt) {
        short8 b = *(const short8*)(Whh + (size_t)(g * 128 + half * 64 + nt * 16 + ci) * 128 + ks * 32 + quad * 8);
        acc[g * 4 + nt] = __builtin_amdgcn_mfma_f32_16x16x32_bf16(a, b, acc[g * 4 + nt], 0, 0, 0);
      }
  }

  float bR[4], bZ[4], bN[4];
#pragma unroll
  for (int nt = 0; nt < 4; ++nt) {
    int c = half * 64 + nt * 16 + ci;
    bR[nt] = BF2F(bhh[c]);
    bZ[nt] = BF2F(bhh[128 + c]);
    bN[nt] = BF2F(bhh[256 + c]);
  }

#pragma unroll
  for (int r = 0; r < 4; ++r) {
    int rr = mr + quad * 4 + r;
    const bf* gs = G + (size_t)rr * gld;
#pragma unroll
    for (int nt = 0; nt < 4; ++nt) {
      int c = half * 64 + nt * 16 + ci;
      float gr = BF2F(gs[c]), gz = BF2F(gs[128 + c]), gnn = BF2F(gs[256 + c]);
      float pre_r = acc[nt][r] + gr + bR[nt];
      float pre_z = acc[4 + nt][r] + gz + bZ[nt];
      float hn_   = acc[8 + nt][r] + bN[nt];
      float rg = fsigmoid(pre_r);
      float zg = fsigmoid(pre_z);
      float ng = ftanh(gnn + rg * hn_);
      float hp = BF2F(Hp[(size_t)rr * 128 + c]);
      float hv = ng + zg * (hp - ng);
      Ho[(size_t)rr * 128 + c] = __float2bfloat16(hv);
      if (HcopyF) HcopyF[(size_t)rr * 128 + c] = hv;
    }
  }
}

// ---------------------------------------------------------------------------
// kSeq v6 (unchanged from R11): grid (1024, 2), 512 thr = 8 waves.
__global__ __launch_bounds__(512, 4) void kSeq(
    const bf* __restrict__ hrnn,
    const bf* __restrict__ Wih_f, const bf* __restrict__ Wih_b,
    const bf* __restrict__ Whh_f, const bf* __restrict__ Whh_b,
    const bf* __restrict__ bih_f, const bf* __restrict__ bih_b,
    const bf* __restrict__ bhh_f, const bf* __restrict__ bhh_b,
    const bf* __restrict__ Wcb, float* __restrict__ L) {
  __shared__ unsigned long long sGiN[16][130];  // [batch][hcol] 3 bf16 gates
  __shared__ bf sH[2][16][136];                 // h ping-pong [batch][hcol]
  __shared__ float sL[16][15][2];               // logits [batch][m][logit]
  __shared__ bf sWc[2][136];                    // Wc rows for this dir

  const int env = blockIdx.x;
  const int dir = blockIdx.y;
  const int tid = threadIdx.x;
  const int wave = tid >> 6, lane = tid & 63;
  const int nh = wave;
  const int quad = lane >> 4, ci = lane & 15;
  const bf* Wih = dir ? Wih_b : Wih_f;
  const bf* Whh = dir ? Whh_b : Whh_f;
  const bf* bih = dir ? bih_b : bih_f;
  const bf* bhh = dir ? bhh_b : bhh_f;
  const int h0q = nh * 16 + quad * 4;

  // ---- Phase 1: gi GEMM (swapped: D[hcol][batch]) ----
  float4v gS[3], gN[3];
#pragma unroll
  for (int i = 0; i < 3; ++i) { gS[i] = {0.f, 0.f, 0.f, 0.f}; gN[i] = {0.f, 0.f, 0.f, 0.f}; }
#pragma unroll
  for (int ks = 0; ks < 4; ++ks) {
    short8 bh = *(const short8*)(hrnn + (size_t)(env * 16 + ci) * 128 + ks * 32 + quad * 8);
#pragma unroll
    for (int g = 0; g < 3; ++g) {
      const bf* wrow = Wih + (size_t)(g * 128 + nh * 16 + ci) * 256 + ks * 32 + quad * 8;
      short8 ws = *(const short8*)(wrow);
      short8 wn = *(const short8*)(wrow + 128);
      gS[g] = __builtin_amdgcn_mfma_f32_16x16x32_bf16(ws, bh, gS[g], 0, 0, 0);
      gN[g] = __builtin_amdgcn_mfma_f32_16x16x32_bf16(wn, bh, gN[g], 0, 0, 0);
    }
  }
#pragma unroll
  for (int g = 0; g < 3; ++g)
#pragma unroll
    for (int r = 0; r < 4; ++r) {
      int c = g * 128 + h0q + r;
      float bv = BF2F(bih[c]);
      if (g < 2) bv += BF2F(bhh[c]);
      gS[g][r] += bv;
    }
#pragma unroll
  for (int r = 0; r < 4; ++r) {
    unsigned long long pk = 0;
#pragma unroll
    for (int g = 0; g < 3; ++g) {
      bf b = __float2bfloat16(gN[g][r]);
      pk |= ((unsigned long long)(*(unsigned short*)&b)) << (16 * g);
    }
    sGiN[ci][h0q + r] = pk;
  }

  {
    bf z = __float2bfloat16(0.f);
    bf* p = &sH[0][0][0];
    for (int i = tid; i < 16 * 136; i += 512) p[i] = z;
    if (tid < 256)
      sWc[tid >> 7][tid & 127] = Wcb[(dir * 2 + (tid >> 7)) * 128 + (tid & 127)];
  }

  // ---- Phase 2: persistent Whh A-frags, constants ----
  short8 Bf[12];
#pragma unroll
  for (int g = 0; g < 3; ++g)
#pragma unroll
    for (int ks = 0; ks < 4; ++ks)
      Bf[g * 4 + ks] =
          *(const short8*)(Whh + (size_t)(g * 128 + nh * 16 + ci) * 128 + ks * 32 + quad * 8);

  float bNc[4];
#pragma unroll
  for (int r = 0; r < 4; ++r) bNc[r] = BF2F(bhh[256 + h0q + r]);

  float hPrev[4];
#pragma unroll
  for (int r = 0; r < 4; ++r) hPrev[r] = 0.f;

  __syncthreads();

  // ---- Phase 3: 15 steps ----
  for (int t = 0; t < 15; ++t) {
    const int cur = t & 1, nxt = cur ^ 1;
    const int m = dir ? (14 - t) : t;
    const int jr = m + ((m >= ci) ? 1 : 0);

    ull2 nb01 = *(const ull2*)&sGiN[jr][h0q];
    ull2 nb23 = *(const ull2*)&sGiN[jr][h0q + 2];

    float4v acc[3];
#pragma unroll
    for (int i = 0; i < 3; ++i) acc[i] = {0.f, 0.f, 0.f, 0.f};
    float4v lacc = {0.f, 0.f, 0.f, 0.f};
#pragma unroll
    for (int ks = 0; ks < 4; ++ks) {
      short8 bh = *(const short8*)&sH[cur][ci][ks * 32 + quad * 8];
#pragma unroll
      for (int g = 0; g < 3; ++g)
        acc[g] = __builtin_amdgcn_mfma_f32_16x16x32_bf16(Bf[g * 4 + ks], bh, acc[g], 0, 0, 0);
      if (nh == 0) {
        short8 wv = *(const short8*)&sWc[ci & 1][ks * 32 + quad * 8];
        lacc = __builtin_amdgcn_mfma_f32_16x16x32_bf16(wv, bh, lacc, 0, 0, 0);
      }
    }
    if (nh == 0 && t > 0 && quad == 0) {
      int mp = dir ? (15 - t) : (t - 1);
      sL[ci][mp][0] = lacc[0];
      sL[ci][mp][1] = lacc[1];
    }

    short4v hv4;
#pragma unroll
    for (int r = 0; r < 4; ++r) {
      unsigned long long nb = (r == 0) ? nb01.x : (r == 1) ? nb01.y
                             : (r == 2) ? nb23.x : nb23.y;
      float pre_r = acc[0][r] + gS[0][r] + upk(nb, 0);
      float pre_z = acc[1][r] + gS[1][r] + upk(nb, 16);
      float gnn   = gS[2][r] + upk(nb, 32);
      float hn_   = acc[2][r] + bNc[r];
      float rg = fsigmoid(pre_r);
      float zg = fsigmoid(pre_z);
      float ng = ftanh(gnn + rg * hn_);
      float hv = ng + zg * (hPrev[r] - ng);
      hPrev[r] = hv;
      bf b = __float2bfloat16(hv);
      hv4[r] = *(short*)&b;
    }
    *(short4v*)&sH[nxt][ci][h0q] = hv4;
    __syncthreads();
  }

  if (nh == 0) {
    float4v lacc = {0.f, 0.f, 0.f, 0.f};
#pragma unroll
    for (int ks = 0; ks < 4; ++ks) {
      short8 bh = *(const short8*)&sH[1][ci][ks * 32 + quad * 8];
      short8 wv = *(const short8*)&sWc[ci & 1][ks * 32 + quad * 8];
      lacc = __builtin_amdgcn_mfma_f32_16x16x32_bf16(wv, bh, lacc, 0, 0, 0);
    }
    if (quad == 0) {
      int mf = dir ? 0 : 14;
      sL[ci][mf][0] = lacc[0];
      sL[ci][mf][1] = lacc[1];
    }
  }
  __syncthreads();

  for (int i = tid; i < 480; i += 512) {
    int row = i / 30, rem = i - row * 30;
    int mm = rem >> 1, l = rem & 1;
    L[(size_t)((env * 16 + row) * 15 + mm) * 4 + dir * 2 + l] = sL[row][mm][l];
  }
}

// ---------------------------------------------------------------------------
// kTail: per block = 4 envs (64 rows). Loop envs: qk MFMA + gumbel + attn ->
// agg staged in sAgg (LDS). Then out14 GEMM reading hrnn (global) + sAgg.
__global__ __launch_bounds__(256) void kTail(
    const bf* __restrict__ h, const bf* __restrict__ Wqk,
    const float* __restrict__ L, const void* __restrict__ guRaw,
    const void* __restrict__ bcRaw, const int* __restrict__ flag,
    const bf* __restrict__ W2p, const void* __restrict__ b2Raw,
    float* __restrict__ out) {
  __shared__ float sh[16 * 132];
  __shared__ float sqk[16 * 64];
  __shared__ float shw[240];
  __shared__ float sw[16 * 16];
  __shared__ bf sAgg[64][136];
  const int b4 = blockIdx.x;
  const int tid = threadIdx.x;
  const int f = *flag;
  const int a = tid >> 4, i = tid & 15;

  for (int e = 0; e < 4; ++e) {
    const int bb = b4 * 4 + e;
    __syncthreads();  // protect LDS reuse across envs
    {
      const int w = tid >> 6, lane = tid & 63;
      const int quad = lane >> 4, ci = lane & 15;
      float4v acc = {0.f, 0.f, 0.f, 0.f};
#pragma unroll
      for (int ks = 0; ks < 4; ++ks) {
        short8 a_ = *(const short8*)(h + (size_t)(bb * 16 + ci) * 128 + ks * 32 + quad * 8);
        short8 b_ = *(const short8*)(Wqk + (size_t)(w * 16 + ci) * 128 + ks * 32 + quad * 8);
        acc = __builtin_amdgcn_mfma_f32_16x16x32_bf16(a_, b_, acc, 0, 0, 0);
      }
#pragma unroll
      for (int r = 0; r < 4; ++r)
        sqk[(quad * 4 + r) * 64 + w * 16 + ci] = acc[r];
    }
    for (int k = tid; k < 2048; k += 256)
      sh[(k >> 7) * 132 + (k & 127)] = BF2F(h[(size_t)bb * 2048 + k]);
    if (tid < 240) {
      int idx = bb * 240 + tid;
      const float* Lp = L + (size_t)idx * 4;
      float l0 = Lp[0] + Lp[2] + rdv(bcRaw, 0, f);
      float l1 = Lp[1] + Lp[3] + rdv(bcRaw, 1, f);
      float u0 = rdv(guRaw, idx * 2, f);
      float u1 = rdv(guRaw, idx * 2 + 1, f);
      float g0 = -__logf(-__logf(u0 + 1e-10f) + 1e-10f);
      float g1 = -__logf(-__logf(u1 + 1e-10f) + 1e-10f);
      shw[tid] = fsigmoid(((l1 + g1) - (l0 + g0)) * 2.0f);
    }
    __syncthreads();

    float s = -1e30f;
    if (i < 15) {
      int j = i + (i >= a);
      float d = 0.f;
#pragma unroll
      for (int c = 0; c < 32; ++c) d += sqk[a * 64 + c] * sqk[j * 64 + 32 + c];
      s = shw[a * 15 + i] * d * 0.17677669529663687f;
    }
    float mx = s;
#pragma unroll
    for (int d = 1; d < 16; d <<= 1) mx = fmaxf(mx, __shfl_xor(mx, d));
    float ex = (i < 15) ? __expf(s - mx) : 0.f;
    float sum = ex;
#pragma unroll
    for (int d = 1; d < 16; d <<= 1) sum += __shfl_xor(sum, d);
    float w = (i < 15) ? (ex * frcp(sum)) * shw[a * 15 + i] : 0.f;
    sw[a * 16 + i] = w;
    __syncthreads();

    float ac[8] = {0, 0, 0, 0, 0, 0, 0, 0};
    for (int mm = 0; mm < 15; ++mm) {
      int jm = mm + (mm >= a);
      float wm = sw[a * 16 + mm];
      const float* shp = &sh[jm * 132 + i * 8];
      float4 h0 = *(const float4*)shp;
      float4 h1 = *(const float4*)(shp + 4);
      ac[0] += wm * h0.x; ac[1] += wm * h0.y; ac[2] += wm * h0.z; ac[3] += wm * h0.w;
      ac[4] += wm * h1.x; ac[5] += wm * h1.y; ac[6] += wm * h1.z; ac[7] += wm * h1.w;
    }
    short8 v;
#pragma unroll
    for (int d = 0; d < 8; ++d) {
      bf b = __float2bfloat16(ac[d]);
      v[d] = *(short*)&b;
    }
    *(short8*)&sAgg[e * 16 + a][i * 8] = v;
  }
  __syncthreads();

  // out14 GEMM: rows b4*64..+63
  {
    const int wave = tid >> 6, lane = tid & 63;
    const int quad = lane >> 4, ci = lane & 15;
    const int mr = b4 * 64 + wave * 16;
    float4v acc = {0.f, 0.f, 0.f, 0.f};
#pragma unroll
    for (int ks = 0; ks < 4; ++ks) {
      short8 a_ = *(const short8*)(h + (size_t)(mr + ci) * 128 + ks * 32 + quad * 8);
      short8 b_ = *(const short8*)(W2p + (size_t)ci * 256 + ks * 32 + quad * 8);
      acc = __builtin_amdgcn_mfma_f32_16x16x32_bf16(a_, b_, acc, 0, 0, 0);
    }
#pragma unroll
    for (int ks = 0; ks < 4; ++ks) {
      short8 a_ = *(const short8*)&sAgg[wave * 16 + ci][ks * 32 + quad * 8];
      short8 b_ = *(const short8*)(W2p + (size_t)ci * 256 + 128 + ks * 32 + quad * 8);
      acc = __builtin_amdgcn_mfma_f32_16x16x32_bf16(a_, b_, acc, 0, 0, 0);
    }
    if (ci < 14) {
      float bv = rdv(b2Raw, ci, f);
#pragma unroll
      for (int r = 0; r < 4; ++r)
        out[(size_t)(mr + quad * 4 + r) * 14 + ci] = acc[r] + bv;
    }
  }
}

// ---------------------------------------------------------------------------
extern "C" void kernel_launch(void* const* d_in, const int* in_sizes, int n_in,
                              void* d_out, int out_size, void* d_ws, size_t ws_size,
                              hipStream_t stream) {
  const size_t OFF_ARENA = 0;          // bf16 arena; L (3.93MB) overlaps dead
                                       //   inputs+hidden [0, 8.38MB) after cell
  const size_t OFF_FLAG  = 10220544;
  const size_t OFF_A     = 10220800;   // gi_c
  const size_t OFF_WQK   = 26998016;   // 16 KB
  const size_t OFF_WCB   = 27014400;   // 1 KB
  const size_t OFF_W2P   = 27410944;   // 8 KB
  const size_t OFF_HRNN  = 27419136;   // 4 MB
  const size_t NEEDED    = 84042240;
  if (ws_size < NEEDED) return;
  if (n_in < 23 || in_sizes[0] != 2097152 || in_sizes[3] != 16384 ||
      in_sizes[5] != 49152 || in_sizes[9] != 98304 || in_sizes[17] != 512 ||
      in_sizes[19] != 4096 || in_sizes[21] != 3584 || out_size != 2326528)
    return;

  char* ws = (char*)d_ws;
  bf*    arena = (bf*)(ws + OFF_ARENA);
  float* L     = (float*)(ws + OFF_ARENA);  // 3.93 MB; valid after cell GRU
  int*   flag  = (int*)(ws + OFF_FLAG);
  bf*    gi_c  = (bf*)(ws + OFF_A + 4194304);
  bf*    Wqk   = (bf*)(ws + OFF_WQK);
  bf*    Wcb   = (bf*)(ws + OFF_WCB);
  bf*    W2p   = (bf*)(ws + OFF_W2P);
  bf*    hrnn  = (bf*)(ws + OFF_HRNN);

  float* out14 = (float*)d_out;
  float* outh  = (float*)d_out + 229376;

  CArgs ca;
  for (int i = 0; i < 23; ++i) { ca.src[i] = d_in[i]; ca.n[i] = AN[i]; ca.off[i] = AO[i]; }
  kConvert<<<dim3(128, 24), 256, 0, stream>>>(ca, flag, arena,
                                              d_in[19], d_in[20], d_in[21], d_in[17],
                                              Wqk, W2p, Wcb);

  const bf* inputs = arena + AO[0];
  const bf* hidden = arena + AO[1];
  const bf* W1     = arena + AO[3];
  const bf* b1     = arena + AO[4];
  const bf* Wih_c  = arena + AO[5];
  const bf* Whh_c  = arena + AO[6];
  const bf* bih_c  = arena + AO[7];
  const bf* bhh_c  = arena + AO[8];
  const bf* Wih_f  = arena + AO[9];
  const bf* Whh_f  = arena + AO[10];
  const bf* bih_f  = arena + AO[11];
  const bf* bhh_f  = arena + AO[12];
  const bf* Wih_b  = arena + AO[13];
  const bf* Whh_b  = arena + AO[14];
  const bf* bih_b  = arena + AO[15];
  const bf* bhh_b  = arena + AO[16];

  // fused x1 + gi_c
  kFused12<<<dim3(256), 256, 0, stream>>>(inputs, W1, b1, Wih_c, bih_c, gi_c);
  // cell GRU: h_rnn (bf16 + fp32 copy to d_out)
  kStep<<<dim3(256, 1, 2), 256, 0, stream>>>(hidden, Whh_c, gi_c, 384, bhh_c,
                                             hrnn, outh);
  // fused gi-GEMM + 15-step bidirectional GRU -> L
  kSeq<<<dim3(1024, 2), 512, 0, stream>>>(hrnn, Wih_f, Wih_b, Whh_f, Whh_b,
                                          bih_f, bih_b, bhh_f, bhh_b, Wcb, L);
  // fused qk + gumbel + attention + out14 GEMM
  kTail<<<dim3(256), 256, 0, stream>>>(hrnn, Wqk, L, d_in[2], d_in[18], flag,
                                       W2p, d_in[22], out14);
}

// Round 5
// 277.463 us; speedup vs baseline: 1.0116x; 1.0116x over previous
//
#include <hip/hip_runtime.h>
#include <hip/hip_bf16.h>

// G2AAgent — ROUND 13: kSeq v7 (fp32 nbr-gi: kill the upk unpack tax).
//  R12 post-mortem: fusion was NEUTRAL (~4us) — dispatch boundaries are
//  ~1-2us, not 8; R2->R3's win was kConvert vectorization. Non-kSeq ~155us
//  is real kernel time we have no counters for; don't churn it blind.
//  kSeq (125us, VALU 54 / MFMA 19): ~25% of VALU issue is upk() unpacking
//  of the 3-bf16-per-u64 sGiN format (9 ops/elem, wave64 = 2cyc/instr).
//  Fixes:
//   (a) sGiN -> raw fp32 [batch][gate][132] (25.3KB): phase-1 writes 3
//       float4 stores of gN accumulators (removes ~40 pack ops + bf16
//       rounding); step reads 3x ds_read_b128, 16B-aligned, 2-way alias
//       only (free per m136). Epilogue: nbR/nbZ/nbN[r] direct adds.
//   (b) L reorganized into 2 dir-planes -> kSeq's 480-float dump is
//       perfectly coalesced (was stride-4 scatter); kTail gumbel updated.
//  Everything else byte-identical to R12.

typedef __attribute__((ext_vector_type(8))) short short8;
typedef __attribute__((ext_vector_type(4))) short short4v;
typedef __attribute__((ext_vector_type(4))) float float4v;

#define BF2F(x) __bfloat162float(x)
typedef __hip_bfloat16 bf;

__device__ __forceinline__ float frcp(float x) {
  return __builtin_amdgcn_rcpf(x);
}
__device__ __forceinline__ float fsigmoid(float x) {
  return frcp(1.f + __expf(-x));
}
__device__ __forceinline__ float ftanh(float x) {
  float e = __expf(2.f * x);
  return 1.f - 2.f * frcp(1.f + e);
}
__device__ __forceinline__ float rdv(const void* p, int i, int f) {
  return f ? ((const float*)p)[i] : BF2F(((const bf*)p)[i]);
}

// ---------------------------------------------------------------------------
static const int AO[23] = {
  0, 2097152, 4194304, 4685824, 4702208, 4702336, 4751488, 4800640, 4801024,
  4801408, 4899712, 4948864, 4949248, 4949632, 5047936, 5097088, 5097472,
  5097856, 5098368, 5098384, 5102480, 5106576, 5110160};
static const int AN[23] = {
  2097152, 2097152, 491520, 16384, 128, 49152, 49152, 384, 384, 98304, 49152,
  384, 384, 98304, 49152, 384, 384, 512, 2, 4096, 4096, 3584, 14};

struct CArgs {
  const void* src[23];
  int n[23];
  int off[23];
};

// ---------------------------------------------------------------------------
// kConvert: per-block self-detect of input dtype (scans first 4096 u16 of
// d_in[0], L2-hot); y<23 = vectorized normalize into arena (skips 2/18/22);
// y==23 = prep (Wqk/W2p/Wcb). Block (0,0) publishes flag for kTail.
__global__ void kConvert(CArgs a, int* __restrict__ flagOut,
                         bf* __restrict__ arena,
                         const void* __restrict__ WqR, const void* __restrict__ WkR,
                         const void* __restrict__ W2R, const void* __restrict__ WcR,
                         bf* __restrict__ Wqk, bf* __restrict__ W2p,
                         bf* __restrict__ Wcb) {
  __shared__ int sflag;
  if (threadIdx.x == 0) sflag = 0;
  __syncthreads();
  {
    const unsigned short* p0 = (const unsigned short*)a.src[0];
    int hit = 0;
    for (int i = threadIdx.x; i < 4096; i += 256) {
      int e = (p0[i] >> 7) & 0xFF;
      if (e >= 0xC0) hit = 1;
    }
    if (hit) atomicOr(&sflag, 1);
  }
  __syncthreads();
  const int f = sflag;
  const int b = blockIdx.y;
  if (b == 0 && blockIdx.x == 0 && threadIdx.x == 0) *flagOut = f;

  if (b == 23) {  // prep
    int idx = blockIdx.x * 256 + threadIdx.x;
    if (idx < 8192) {
      int r = idx >> 7, c = idx & 127;
      float v = (r < 32) ? rdv(WqR, r * 128 + c, f) : rdv(WkR, (r - 32) * 128 + c, f);
      Wqk[idx] = __float2bfloat16(v);
    }
    if (idx < 4096)
      W2p[idx] = __float2bfloat16((idx < 3584) ? rdv(W2R, idx, f) : 0.f);
    if (idx < 512) {
      int dir = idx >> 8, l = (idx >> 7) & 1, k = idx & 127;
      Wcb[idx] = __float2bfloat16(rdv(WcR, l * 256 + dir * 128 + k, f));
    }
    return;
  }
  if (b == 2 || b == 18 || b == 22) return;  // consumed raw via rdv
  const int n = a.n[b];
  const int nv = n & ~7;
  bf* dst = arena + a.off[b];
  const int gid = blockIdx.x * 256 + threadIdx.x;
  const int gs = gridDim.x * 256;
  if (f) {
    const float* s = (const float*)a.src[b];
    for (int i = gid * 8; i < nv; i += gs * 8) {
      float4 x0 = *(const float4*)(s + i);
      float4 x1 = *(const float4*)(s + i + 4);
      short8 v;
      bf t;
      t = __float2bfloat16(x0.x); v[0] = *(short*)&t;
      t = __float2bfloat16(x0.y); v[1] = *(short*)&t;
      t = __float2bfloat16(x0.z); v[2] = *(short*)&t;
      t = __float2bfloat16(x0.w); v[3] = *(short*)&t;
      t = __float2bfloat16(x1.x); v[4] = *(short*)&t;
      t = __float2bfloat16(x1.y); v[5] = *(short*)&t;
      t = __float2bfloat16(x1.z); v[6] = *(short*)&t;
      t = __float2bfloat16(x1.w); v[7] = *(short*)&t;
      *(short8*)(dst + i) = v;
    }
    for (int i = nv + gid; i < n; i += gs) dst[i] = __float2bfloat16(s[i]);
  } else {
    const short8* s = (const short8*)a.src[b];
    short8* d = (short8*)dst;
    for (int i = gid; i * 8 < nv; i += gs) d[i] = s[i];
    const unsigned short* ss = (const unsigned short*)a.src[b];
    unsigned short* ds = (unsigned short*)dst;
    for (int i = nv + gid; i < n; i += gs) ds[i] = ss[i];
  }
}

// ---------------------------------------------------------------------------
// kFused12: x1 = relu(inputs[64xIN] @ W1^T + b1) per block (64 rows), staged
// per-wave in LDS (swapped MFMA -> b64 stores, same-wave readback, no
// barrier), then gi_c[64x384] = x1 @ Wih_c^T streamed in 64-col groups.
__global__ __launch_bounds__(256) void kFused12(
    const bf* __restrict__ inputs, const bf* __restrict__ W1,
    const bf* __restrict__ b1, const bf* __restrict__ Wih,
    const bf* __restrict__ bih, bf* __restrict__ gi) {
  __shared__ bf sX[4][16][136];  // per-wave x1 tile, 17.4 KB
  const int tid = threadIdx.x;
  const int wave = tid >> 6, lane = tid & 63;
  const int quad = lane >> 4, ci = lane & 15;
  const int row0 = blockIdx.x * 64 + wave * 16;

  float4v xa[8];
#pragma unroll
  for (int i = 0; i < 8; ++i) xa[i] = {0.f, 0.f, 0.f, 0.f};
#pragma unroll
  for (int ks = 0; ks < 4; ++ks) {
    short8 inr = *(const short8*)(inputs + (size_t)(row0 + ci) * 128 + ks * 32 + quad * 8);
#pragma unroll
    for (int ct = 0; ct < 8; ++ct) {
      short8 wfr = *(const short8*)(W1 + (size_t)(ct * 16 + ci) * 128 + ks * 32 + quad * 8);
      xa[ct] = __builtin_amdgcn_mfma_f32_16x16x32_bf16(wfr, inr, xa[ct], 0, 0, 0);
    }
  }
#pragma unroll
  for (int ct = 0; ct < 8; ++ct) {
    short4v v4;
#pragma unroll
    for (int r = 0; r < 4; ++r) {
      float v = xa[ct][r] + BF2F(b1[ct * 16 + quad * 4 + r]);
      v = fmaxf(v, 0.f);
      bf t = __float2bfloat16(v);
      v4[r] = *(short*)&t;
    }
    *(short4v*)&sX[wave][ci][ct * 16 + quad * 4] = v4;
  }
  short8 af[4];
#pragma unroll
  for (int ks = 0; ks < 4; ++ks)
    af[ks] = *(const short8*)&sX[wave][ci][ks * 32 + quad * 8];

  for (int cg = 0; cg < 6; ++cg) {
    float4v acc[4];
#pragma unroll
    for (int i = 0; i < 4; ++i) acc[i] = {0.f, 0.f, 0.f, 0.f};
#pragma unroll
    for (int ks = 0; ks < 4; ++ks)
#pragma unroll
      for (int nt = 0; nt < 4; ++nt) {
        short8 b = *(const short8*)(Wih + (size_t)(cg * 64 + nt * 16 + ci) * 128 + ks * 32 + quad * 8);
        acc[nt] = __builtin_amdgcn_mfma_f32_16x16x32_bf16(af[ks], b, acc[nt], 0, 0, 0);
      }
#pragma unroll
    for (int nt = 0; nt < 4; ++nt) {
      int col = cg * 64 + nt * 16 + ci;
      float bv = BF2F(bih[col]);
#pragma unroll
      for (int r = 0; r < 4; ++r)
        gi[(size_t)(row0 + quad * 4 + r) * 384 + col] = __float2bfloat16(acc[nt][r] + bv);
    }
  }
}

// ---------------------------------------------------------------------------
// kStep: single GRU step (cell GRU only).
__global__ __launch_bounds__(256, 4) void kStep(
    const bf* __restrict__ Hp, const bf* __restrict__ Whh,
    const bf* __restrict__ G, int gld,
    const bf* __restrict__ bhh,
    bf* __restrict__ Ho, float* __restrict__ HcopyF) {
  const int half = blockIdx.z;
  const int tid = threadIdx.x;
  const int wave = tid >> 6, lane = tid & 63;
  const int quad = lane >> 4, ci = lane & 15;
  const int mr = blockIdx.x * 64 + wave * 16;

  float4v acc[12];
#pragma unroll
  for (int i = 0; i < 12; ++i) acc[i] = {0.f, 0.f, 0.f, 0.f};

#pragma unroll
  for (int ks = 0; ks < 4; ++ks) {
    short8 a = *(const short8*)(Hp + (size_t)(mr + ci) * 128 + ks * 32 + quad * 8);
#pragma unroll
    for (int g = 0; g < 3; ++g)
#pragma unroll
      for (int nt = 0; nt < 4; ++nt) {
        short8 b = *(const short8*)(Whh + (size_t)(g * 128 + half * 64 + nt * 16 + ci) * 128 + ks * 32 + quad * 8);
        acc[g * 4 + nt] = __builtin_amdgcn_mfma_f32_16x16x32_bf16(a, b, acc[g * 4 + nt], 0, 0, 0);
      }
  }

  float bR[4], bZ[4], bN[4];
#pragma unroll
  for (int nt = 0; nt < 4; ++nt) {
    int c = half * 64 + nt * 16 + ci;
    bR[nt] = BF2F(bhh[c]);
    bZ[nt] = BF2F(bhh[128 + c]);
    bN[nt] = BF2F(bhh[256 + c]);
  }

#pragma unroll
  for (int r = 0; r < 4; ++r) {
    int rr = mr + quad * 4 + r;
    const bf* gs = G + (size_t)rr * gld;
#pragma unroll
    for (int nt = 0; nt < 4; ++nt) {
      int c = half * 64 + nt * 16 + ci;
      float gr = BF2F(gs[c]), gz = BF2F(gs[128 + c]), gnn = BF2F(gs[256 + c]);
      float pre_r = acc[nt][r] + gr + bR[nt];
      float pre_z = acc[4 + nt][r] + gz + bZ[nt];
      float hn_   = acc[8 + nt][r] + bN[nt];
      float rg = fsigmoid(pre_r);
      float zg = fsigmoid(pre_z);
      float ng = ftanh(gnn + rg * hn_);
      float hp = BF2F(Hp[(size_t)rr * 128 + c]);
      float hv = ng + zg * (hp - ng);
      Ho[(size_t)rr * 128 + c] = __float2bfloat16(hv);
      if (HcopyF) HcopyF[(size_t)rr * 128 + c] = hv;
    }
  }
}

// ---------------------------------------------------------------------------
// kSeq v7: grid (1024, 2), 512 thr = 8 waves. Operand-swapped MFMAs
// (D[hcol][batch]); nbr-gi kept as RAW FP32 in sGiN[batch][gate][132]
// (no pack/unpack); L written as 2 dir-planes, fully coalesced.
__global__ __launch_bounds__(512, 4) void kSeq(
    const bf* __restrict__ hrnn,
    const bf* __restrict__ Wih_f, const bf* __restrict__ Wih_b,
    const bf* __restrict__ Whh_f, const bf* __restrict__ Whh_b,
    const bf* __restrict__ bih_f, const bf* __restrict__ bih_b,
    const bf* __restrict__ bhh_f, const bf* __restrict__ bhh_b,
    const bf* __restrict__ Wcb, float* __restrict__ L) {
  __shared__ float sGiN[16][3][132];            // [batch][gate][hcol] fp32 25.3KB
  __shared__ bf sH[2][16][136];                 // h ping-pong [batch][hcol]
  __shared__ float sL[16][15][2];               // logits [batch][m][logit]
  __shared__ bf sWc[2][136];                    // Wc rows for this dir

  const int env = blockIdx.x;
  const int dir = blockIdx.y;
  const int tid = threadIdx.x;
  const int wave = tid >> 6, lane = tid & 63;
  const int nh = wave;
  const int quad = lane >> 4, ci = lane & 15;
  const bf* Wih = dir ? Wih_b : Wih_f;
  const bf* Whh = dir ? Whh_b : Whh_f;
  const bf* bih = dir ? bih_b : bih_f;
  const bf* bhh = dir ? bhh_b : bhh_f;
  const int h0q = nh * 16 + quad * 4;

  // ---- Phase 1: gi GEMM (swapped: D[hcol][batch]) ----
  float4v gS[3], gN[3];
#pragma unroll
  for (int i = 0; i < 3; ++i) { gS[i] = {0.f, 0.f, 0.f, 0.f}; gN[i] = {0.f, 0.f, 0.f, 0.f}; }
#pragma unroll
  for (int ks = 0; ks < 4; ++ks) {
    short8 bh = *(const short8*)(hrnn + (size_t)(env * 16 + ci) * 128 + ks * 32 + quad * 8);
#pragma unroll
    for (int g = 0; g < 3; ++g) {
      const bf* wrow = Wih + (size_t)(g * 128 + nh * 16 + ci) * 256 + ks * 32 + quad * 8;
      short8 ws = *(const short8*)(wrow);
      short8 wn = *(const short8*)(wrow + 128);
      gS[g] = __builtin_amdgcn_mfma_f32_16x16x32_bf16(ws, bh, gS[g], 0, 0, 0);
      gN[g] = __builtin_amdgcn_mfma_f32_16x16x32_bf16(wn, bh, gN[g], 0, 0, 0);
    }
  }
#pragma unroll
  for (int g = 0; g < 3; ++g)
#pragma unroll
    for (int r = 0; r < 4; ++r) {
      int c = g * 128 + h0q + r;
      float bv = BF2F(bih[c]);
      if (g < 2) bv += BF2F(bhh[c]);
      gS[g][r] += bv;
    }
  // nbr-gi straight to LDS as fp32 (one b128 store per gate)
#pragma unroll
  for (int g = 0; g < 3; ++g)
    *(float4v*)&sGiN[ci][g][h0q] = gN[g];

  {
    bf z = __float2bfloat16(0.f);
    bf* p = &sH[0][0][0];
    for (int i = tid; i < 16 * 136; i += 512) p[i] = z;
    if (tid < 256)
      sWc[tid >> 7][tid & 127] = Wcb[(dir * 2 + (tid >> 7)) * 128 + (tid & 127)];
  }

  // ---- Phase 2: persistent Whh A-frags, constants ----
  short8 Bf[12];
#pragma unroll
  for (int g = 0; g < 3; ++g)
#pragma unroll
    for (int ks = 0; ks < 4; ++ks)
      Bf[g * 4 + ks] =
          *(const short8*)(Whh + (size_t)(g * 128 + nh * 16 + ci) * 128 + ks * 32 + quad * 8);

  float bNc[4];
#pragma unroll
  for (int r = 0; r < 4; ++r) bNc[r] = BF2F(bhh[256 + h0q + r]);

  float hPrev[4];
#pragma unroll
  for (int r = 0; r < 4; ++r) hPrev[r] = 0.f;

  __syncthreads();

  // ---- Phase 3: 15 steps ----
  for (int t = 0; t < 15; ++t) {
    const int cur = t & 1, nxt = cur ^ 1;
    const int m = dir ? (14 - t) : t;
    const int jr = m + ((m >= ci) ? 1 : 0);

    float4v nbR = *(const float4v*)&sGiN[jr][0][h0q];
    float4v nbZ = *(const float4v*)&sGiN[jr][1][h0q];
    float4v nbN = *(const float4v*)&sGiN[jr][2][h0q];

    float4v acc[3];
#pragma unroll
    for (int i = 0; i < 3; ++i) acc[i] = {0.f, 0.f, 0.f, 0.f};
    float4v lacc = {0.f, 0.f, 0.f, 0.f};
#pragma unroll
    for (int ks = 0; ks < 4; ++ks) {
      short8 bh = *(const short8*)&sH[cur][ci][ks * 32 + quad * 8];
#pragma unroll
      for (int g = 0; g < 3; ++g)
        acc[g] = __builtin_amdgcn_mfma_f32_16x16x32_bf16(Bf[g * 4 + ks], bh, acc[g], 0, 0, 0);
      if (nh == 0) {
        short8 wv = *(const short8*)&sWc[ci & 1][ks * 32 + quad * 8];
        lacc = __builtin_amdgcn_mfma_f32_16x16x32_bf16(wv, bh, lacc, 0, 0, 0);
      }
    }
    if (nh == 0 && t > 0 && quad == 0) {
      int mp = dir ? (15 - t) : (t - 1);
      sL[ci][mp][0] = lacc[0];
      sL[ci][mp][1] = lacc[1];
    }

    short4v hv4;
#pragma unroll
    for (int r = 0; r < 4; ++r) {
      float pre_r = acc[0][r] + gS[0][r] + nbR[r];
      float pre_z = acc[1][r] + gS[1][r] + nbZ[r];
      float gnn   = gS[2][r] + nbN[r];
      float hn_   = acc[2][r] + bNc[r];
      float rg = fsigmoid(pre_r);
      float zg = fsigmoid(pre_z);
      float ng = ftanh(gnn + rg * hn_);
      float hv = ng + zg * (hPrev[r] - ng);
      hPrev[r] = hv;
      bf b = __float2bfloat16(hv);
      hv4[r] = *(short*)&b;
    }
    *(short4v*)&sH[nxt][ci][h0q] = hv4;
    __syncthreads();
  }

  if (nh == 0) {
    float4v lacc = {0.f, 0.f, 0.f, 0.f};
#pragma unroll
    for (int ks = 0; ks < 4; ++ks) {
      short8 bh = *(const short8*)&sH[1][ci][ks * 32 + quad * 8];
      short8 wv = *(const short8*)&sWc[ci & 1][ks * 32 + quad * 8];
      lacc = __builtin_amdgcn_mfma_f32_16x16x32_bf16(wv, bh, lacc, 0, 0, 0);
    }
    if (quad == 0) {
      int mf = dir ? 0 : 14;
      sL[ci][mf][0] = lacc[0];
      sL[ci][mf][1] = lacc[1];
    }
  }
  __syncthreads();

  // coalesced dump: L[dir plane][ (env*16+row)*15+mm )*2 + l ], addr == i
  {
    float* Ld = L + (size_t)dir * 491520 + (size_t)env * 480;
    for (int i = tid; i < 480; i += 512) {
      int row = i / 30, rem = i - row * 30;
      int mm = rem >> 1, l = rem & 1;
      Ld[i] = sL[row][mm][l];
    }
  }
}

// ---------------------------------------------------------------------------
// kTail: per block = 4 envs (64 rows). Loop envs: qk MFMA + gumbel + attn ->
// agg staged in sAgg (LDS). Then out14 GEMM reading hrnn (global) + sAgg.
__global__ __launch_bounds__(256) void kTail(
    const bf* __restrict__ h, const bf* __restrict__ Wqk,
    const float* __restrict__ L, const void* __restrict__ guRaw,
    const void* __restrict__ bcRaw, const int* __restrict__ flag,
    const bf* __restrict__ W2p, const void* __restrict__ b2Raw,
    float* __restrict__ out) {
  __shared__ float sh[16 * 132];
  __shared__ float sqk[16 * 64];
  __shared__ float shw[240];
  __shared__ float sw[16 * 16];
  __shared__ bf sAgg[64][136];
  const int b4 = blockIdx.x;
  const int tid = threadIdx.x;
  const int f = *flag;
  const int a = tid >> 4, i = tid & 15;

  for (int e = 0; e < 4; ++e) {
    const int bb = b4 * 4 + e;
    __syncthreads();  // protect LDS reuse across envs
    {
      const int w = tid >> 6, lane = tid & 63;
      const int quad = lane >> 4, ci = lane & 15;
      float4v acc = {0.f, 0.f, 0.f, 0.f};
#pragma unroll
      for (int ks = 0; ks < 4; ++ks) {
        short8 a_ = *(const short8*)(h + (size_t)(bb * 16 + ci) * 128 + ks * 32 + quad * 8);
        short8 b_ = *(const short8*)(Wqk + (size_t)(w * 16 + ci) * 128 + ks * 32 + quad * 8);
        acc = __builtin_amdgcn_mfma_f32_16x16x32_bf16(a_, b_, acc, 0, 0, 0);
      }
#pragma unroll
      for (int r = 0; r < 4; ++r)
        sqk[(quad * 4 + r) * 64 + w * 16 + ci] = acc[r];
    }
    for (int k = tid; k < 2048; k += 256)
      sh[(k >> 7) * 132 + (k & 127)] = BF2F(h[(size_t)bb * 2048 + k]);
    if (tid < 240) {
      int idx = bb * 240 + tid;
      float l0 = L[(size_t)idx * 2]     + L[491520 + (size_t)idx * 2]     + rdv(bcRaw, 0, f);
      float l1 = L[(size_t)idx * 2 + 1] + L[491520 + (size_t)idx * 2 + 1] + rdv(bcRaw, 1, f);
      float u0 = rdv(guRaw, idx * 2, f);
      float u1 = rdv(guRaw, idx * 2 + 1, f);
      float g0 = -__logf(-__logf(u0 + 1e-10f) + 1e-10f);
      float g1 = -__logf(-__logf(u1 + 1e-10f) + 1e-10f);
      shw[tid] = fsigmoid(((l1 + g1) - (l0 + g0)) * 2.0f);
    }
    __syncthreads();

    float s = -1e30f;
    if (i < 15) {
      int j = i + (i >= a);
      float d = 0.f;
#pragma unroll
      for (int c = 0; c < 32; ++c) d += sqk[a * 64 + c] * sqk[j * 64 + 32 + c];
      s = shw[a * 15 + i] * d * 0.17677669529663687f;
    }
    float mx = s;
#pragma unroll
    for (int d = 1; d < 16; d <<= 1) mx = fmaxf(mx, __shfl_xor(mx, d));
    float ex = (i < 15) ? __expf(s - mx) : 0.f;
    float sum = ex;
#pragma unroll
    for (int d = 1; d < 16; d <<= 1) sum += __shfl_xor(sum, d);
    float w = (i < 15) ? (ex * frcp(sum)) * shw[a * 15 + i] : 0.f;
    sw[a * 16 + i] = w;
    __syncthreads();

    float ac[8] = {0, 0, 0, 0, 0, 0, 0, 0};
    for (int mm = 0; mm < 15; ++mm) {
      int jm = mm + (mm >= a);
      float wm = sw[a * 16 + mm];
      const float* shp = &sh[jm * 132 + i * 8];
      float4 h0 = *(const float4*)shp;
      float4 h1 = *(const float4*)(shp + 4);
      ac[0] += wm * h0.x; ac[1] += wm * h0.y; ac[2] += wm * h0.z; ac[3] += wm * h0.w;
      ac[4] += wm * h1.x; ac[5] += wm * h1.y; ac[6] += wm * h1.z; ac[7] += wm * h1.w;
    }
    short8 v;
#pragma unroll
    for (int d = 0; d < 8; ++d) {
      bf b = __float2bfloat16(ac[d]);
      v[d] = *(short*)&b;
    }
    *(short8*)&sAgg[e * 16 + a][i * 8] = v;
  }
  __syncthreads();

  // out14 GEMM: rows b4*64..+63
  {
    const int wave = tid >> 6, lane = tid & 63;
    const int quad = lane >> 4, ci = lane & 15;
    const int mr = b4 * 64 + wave * 16;
    float4v acc = {0.f, 0.f, 0.f, 0.f};
#pragma unroll
    for (int ks = 0; ks < 4; ++ks) {
      short8 a_ = *(const short8*)(h + (size_t)(mr + ci) * 128 + ks * 32 + quad * 8);
      short8 b_ = *(const short8*)(W2p + (size_t)ci * 256 + ks * 32 + quad * 8);
      acc = __builtin_amdgcn_mfma_f32_16x16x32_bf16(a_, b_, acc, 0, 0, 0);
    }
#pragma unroll
    for (int ks = 0; ks < 4; ++ks) {
      short8 a_ = *(const short8*)&sAgg[wave * 16 + ci][ks * 32 + quad * 8];
      short8 b_ = *(const short8*)(W2p + (size_t)ci * 256 + 128 + ks * 32 + quad * 8);
      acc = __builtin_amdgcn_mfma_f32_16x16x32_bf16(a_, b_, acc, 0, 0, 0);
    }
    if (ci < 14) {
      float bv = rdv(b2Raw, ci, f);
#pragma unroll
      for (int r = 0; r < 4; ++r)
        out[(size_t)(mr + quad * 4 + r) * 14 + ci] = acc[r] + bv;
    }
  }
}

// ---------------------------------------------------------------------------
extern "C" void kernel_launch(void* const* d_in, const int* in_sizes, int n_in,
                              void* d_out, int out_size, void* d_ws, size_t ws_size,
                              hipStream_t stream) {
  const size_t OFF_ARENA = 0;          // bf16 arena; L (3.93MB) overlaps dead
                                       //   inputs+hidden [0, 8.38MB) after cell
  const size_t OFF_FLAG  = 10220544;
  const size_t OFF_A     = 10220800;   // gi_c
  const size_t OFF_WQK   = 26998016;   // 16 KB
  const size_t OFF_WCB   = 27014400;   // 1 KB
  const size_t OFF_W2P   = 27410944;   // 8 KB
  const size_t OFF_HRNN  = 27419136;   // 4 MB
  const size_t NEEDED    = 84042240;
  if (ws_size < NEEDED) return;
  if (n_in < 23 || in_sizes[0] != 2097152 || in_sizes[3] != 16384 ||
      in_sizes[5] != 49152 || in_sizes[9] != 98304 || in_sizes[17] != 512 ||
      in_sizes[19] != 4096 || in_sizes[21] != 3584 || out_size != 2326528)
    return;

  char* ws = (char*)d_ws;
  bf*    arena = (bf*)(ws + OFF_ARENA);
  float* L     = (float*)(ws + OFF_ARENA);  // 3.93 MB; valid after cell GRU
  int*   flag  = (int*)(ws + OFF_FLAG);
  bf*    gi_c  = (bf*)(ws + OFF_A + 4194304);
  bf*    Wqk   = (bf*)(ws + OFF_WQK);
  bf*    Wcb   = (bf*)(ws + OFF_WCB);
  bf*    W2p   = (bf*)(ws + OFF_W2P);
  bf*    hrnn  = (bf*)(ws + OFF_HRNN);

  float* out14 = (float*)d_out;
  float* outh  = (float*)d_out + 229376;

  CArgs ca;
  for (int i = 0; i < 23; ++i) { ca.src[i] = d_in[i]; ca.n[i] = AN[i]; ca.off[i] = AO[i]; }
  kConvert<<<dim3(128, 24), 256, 0, stream>>>(ca, flag, arena,
                                              d_in[19], d_in[20], d_in[21], d_in[17],
                                              Wqk, W2p, Wcb);

  const bf* inputs = arena + AO[0];
  const bf* hidden = arena + AO[1];
  const bf* W1     = arena + AO[3];
  const bf* b1     = arena + AO[4];
  const bf* Wih_c  = arena + AO[5];
  const bf* Whh_c  = arena + AO[6];
  const bf* bih_c  = arena + AO[7];
  const bf* bhh_c  = arena + AO[8];
  const bf* Wih_f  = arena + AO[9];
  const bf* Whh_f  = arena + AO[10];
  const bf* bih_f  = arena + AO[11];
  const bf* bhh_f  = arena + AO[12];
  const bf* Wih_b  = arena + AO[13];
  const bf* Whh_b  = arena + AO[14];
  const bf* bih_b  = arena + AO[15];
  const bf* bhh_b  = arena + AO[16];

  // fused x1 + gi_c
  kFused12<<<dim3(256), 256, 0, stream>>>(inputs, W1, b1, Wih_c, bih_c, gi_c);
  // cell GRU: h_rnn (bf16 + fp32 copy to d_out)
  kStep<<<dim3(256, 1, 2), 256, 0, stream>>>(hidden, Whh_c, gi_c, 384, bhh_c,
                                             hrnn, outh);
  // fused gi-GEMM + 15-step bidirectional GRU -> L (2 dir planes)
  kSeq<<<dim3(1024, 2), 512, 0, stream>>>(hrnn, Wih_f, Wih_b, Whh_f, Whh_b,
                                          bih_f, bih_b, bhh_f, bhh_b, Wcb, L);
  // fused qk + gumbel + attention + out14 GEMM
  kTail<<<dim3(256), 256, 0, stream>>>(hrnn, Wqk, L, d_in[2], d_in[18], flag,
                                       W2p, d_in[22], out14);
}

// Round 6
// 267.427 us; speedup vs baseline: 1.0496x; 1.0375x over previous
//
#include <hip/hip_runtime.h>
#include <hip/hip_bf16.h>

// G2AAgent — ROUND 14: parallelism fix for the invisible 155us.
//  R13 post-mortem: kSeq 125->118.8 (VALU diet diminishing). Non-kSeq has
//  been ~155-183us for FIVE rounds while visible work shrank; estimates put
//  its compute at ~50us. Root cause found by re-reading my own launches:
//  kFused12 and kTail are 256-block grids on a 256-CU chip (1 block/CU,
//  1 wave/SIMD — zero TLP, serial multi-phase bodies), kStep 2 blocks/CU.
//  Guideline-1 violation introduced by R12's fusion; counters never showed
//  it (top-5 = kSeq only). Fix, keeping all fusion + bit-identical math:
//   (a) kFused12: 1024 blocks x 16 rows; stage A waves own 2/8 x1 tiles
//       (shared sX, one barrier); stage B waves own 6/24 gi tiles.
//   (b) kStep: 1024 blocks x 32 rows; wave&1 = row half, wave>>1 = nt half
//       (acc 12->6, fewer VGPRs, more waves/CU).
//   (c) kTail: 1024 blocks x 1 env (R11's proven attn grid) + out-GEMM on
//       wave 0.
//  kSeq (v7) and kConvert untouched.

typedef __attribute__((ext_vector_type(8))) short short8;
typedef __attribute__((ext_vector_type(4))) short short4v;
typedef __attribute__((ext_vector_type(4))) float float4v;

#define BF2F(x) __bfloat162float(x)
typedef __hip_bfloat16 bf;

__device__ __forceinline__ float frcp(float x) {
  return __builtin_amdgcn_rcpf(x);
}
__device__ __forceinline__ float fsigmoid(float x) {
  return frcp(1.f + __expf(-x));
}
__device__ __forceinline__ float ftanh(float x) {
  float e = __expf(2.f * x);
  return 1.f - 2.f * frcp(1.f + e);
}
__device__ __forceinline__ float rdv(const void* p, int i, int f) {
  return f ? ((const float*)p)[i] : BF2F(((const bf*)p)[i]);
}

// ---------------------------------------------------------------------------
static const int AO[23] = {
  0, 2097152, 4194304, 4685824, 4702208, 4702336, 4751488, 4800640, 4801024,
  4801408, 4899712, 4948864, 4949248, 4949632, 5047936, 5097088, 5097472,
  5097856, 5098368, 5098384, 5102480, 5106576, 5110160};
static const int AN[23] = {
  2097152, 2097152, 491520, 16384, 128, 49152, 49152, 384, 384, 98304, 49152,
  384, 384, 98304, 49152, 384, 384, 512, 2, 4096, 4096, 3584, 14};

struct CArgs {
  const void* src[23];
  int n[23];
  int off[23];
};

// ---------------------------------------------------------------------------
// kConvert: per-block self-detect of input dtype; y<23 = vectorized
// normalize into arena (skips 2/18/22); y==23 = prep (Wqk/W2p/Wcb).
__global__ void kConvert(CArgs a, int* __restrict__ flagOut,
                         bf* __restrict__ arena,
                         const void* __restrict__ WqR, const void* __restrict__ WkR,
                         const void* __restrict__ W2R, const void* __restrict__ WcR,
                         bf* __restrict__ Wqk, bf* __restrict__ W2p,
                         bf* __restrict__ Wcb) {
  __shared__ int sflag;
  if (threadIdx.x == 0) sflag = 0;
  __syncthreads();
  {
    const unsigned short* p0 = (const unsigned short*)a.src[0];
    int hit = 0;
    for (int i = threadIdx.x; i < 4096; i += 256) {
      int e = (p0[i] >> 7) & 0xFF;
      if (e >= 0xC0) hit = 1;
    }
    if (hit) atomicOr(&sflag, 1);
  }
  __syncthreads();
  const int f = sflag;
  const int b = blockIdx.y;
  if (b == 0 && blockIdx.x == 0 && threadIdx.x == 0) *flagOut = f;

  if (b == 23) {  // prep
    int idx = blockIdx.x * 256 + threadIdx.x;
    if (idx < 8192) {
      int r = idx >> 7, c = idx & 127;
      float v = (r < 32) ? rdv(WqR, r * 128 + c, f) : rdv(WkR, (r - 32) * 128 + c, f);
      Wqk[idx] = __float2bfloat16(v);
    }
    if (idx < 4096)
      W2p[idx] = __float2bfloat16((idx < 3584) ? rdv(W2R, idx, f) : 0.f);
    if (idx < 512) {
      int dir = idx >> 8, l = (idx >> 7) & 1, k = idx & 127;
      Wcb[idx] = __float2bfloat16(rdv(WcR, l * 256 + dir * 128 + k, f));
    }
    return;
  }
  if (b == 2 || b == 18 || b == 22) return;  // consumed raw via rdv
  const int n = a.n[b];
  const int nv = n & ~7;
  bf* dst = arena + a.off[b];
  const int gid = blockIdx.x * 256 + threadIdx.x;
  const int gs = gridDim.x * 256;
  if (f) {
    const float* s = (const float*)a.src[b];
    for (int i = gid * 8; i < nv; i += gs * 8) {
      float4 x0 = *(const float4*)(s + i);
      float4 x1 = *(const float4*)(s + i + 4);
      short8 v;
      bf t;
      t = __float2bfloat16(x0.x); v[0] = *(short*)&t;
      t = __float2bfloat16(x0.y); v[1] = *(short*)&t;
      t = __float2bfloat16(x0.z); v[2] = *(short*)&t;
      t = __float2bfloat16(x0.w); v[3] = *(short*)&t;
      t = __float2bfloat16(x1.x); v[4] = *(short*)&t;
      t = __float2bfloat16(x1.y); v[5] = *(short*)&t;
      t = __float2bfloat16(x1.z); v[6] = *(short*)&t;
      t = __float2bfloat16(x1.w); v[7] = *(short*)&t;
      *(short8*)(dst + i) = v;
    }
    for (int i = nv + gid; i < n; i += gs) dst[i] = __float2bfloat16(s[i]);
  } else {
    const short8* s = (const short8*)a.src[b];
    short8* d = (short8*)dst;
    for (int i = gid; i * 8 < nv; i += gs) d[i] = s[i];
    const unsigned short* ss = (const unsigned short*)a.src[b];
    unsigned short* ds = (unsigned short*)dst;
    for (int i = nv + gid; i < n; i += gs) ds[i] = ss[i];
  }
}

// ---------------------------------------------------------------------------
// kFused12 v2: 1024 blocks x 16 rows. Stage A: wave w computes x1 col-tiles
// {2w, 2w+1} (swapped MFMA, D[col][row]) into shared sX[16][136]; barrier;
// stage B: wave w computes gi col-tiles {6w..6w+5} reading sX A-frags.
__global__ __launch_bounds__(256) void kFused12(
    const bf* __restrict__ inputs, const bf* __restrict__ W1,
    const bf* __restrict__ b1, const bf* __restrict__ Wih,
    const bf* __restrict__ bih, bf* __restrict__ gi) {
  __shared__ bf sX[16][136];  // x1 tile, 4.25 KB
  const int tid = threadIdx.x;
  const int wave = tid >> 6, lane = tid & 63;
  const int quad = lane >> 4, ci = lane & 15;
  const int row0 = blockIdx.x * 16;

  // stage A: swapped -> D[x1col][row]; wave owns 2 col-tiles.
  float4v xa[2];
#pragma unroll
  for (int i = 0; i < 2; ++i) xa[i] = {0.f, 0.f, 0.f, 0.f};
#pragma unroll
  for (int ks = 0; ks < 4; ++ks) {
    short8 inr = *(const short8*)(inputs + (size_t)(row0 + ci) * 128 + ks * 32 + quad * 8);
#pragma unroll
    for (int c2 = 0; c2 < 2; ++c2) {
      int ct = wave * 2 + c2;
      short8 wfr = *(const short8*)(W1 + (size_t)(ct * 16 + ci) * 128 + ks * 32 + quad * 8);
      xa[c2] = __builtin_amdgcn_mfma_f32_16x16x32_bf16(wfr, inr, xa[c2], 0, 0, 0);
    }
  }
#pragma unroll
  for (int c2 = 0; c2 < 2; ++c2) {
    int ct = wave * 2 + c2;
    short4v v4;
#pragma unroll
    for (int r = 0; r < 4; ++r) {
      float v = xa[c2][r] + BF2F(b1[ct * 16 + quad * 4 + r]);
      v = fmaxf(v, 0.f);
      bf t = __float2bfloat16(v);
      v4[r] = *(short*)&t;
    }
    *(short4v*)&sX[ci][ct * 16 + quad * 4] = v4;
  }
  __syncthreads();

  short8 af[4];
#pragma unroll
  for (int ks = 0; ks < 4; ++ks)
    af[ks] = *(const short8*)&sX[ci][ks * 32 + quad * 8];

  // stage B: gi (standard D[row][col]), wave owns 6 col-tiles of 16.
  float4v acc[6];
#pragma unroll
  for (int i = 0; i < 6; ++i) acc[i] = {0.f, 0.f, 0.f, 0.f};
#pragma unroll
  for (int ks = 0; ks < 4; ++ks)
#pragma unroll
    for (int j = 0; j < 6; ++j) {
      short8 b = *(const short8*)(Wih + (size_t)((wave * 6 + j) * 16 + ci) * 128 + ks * 32 + quad * 8);
      acc[j] = __builtin_amdgcn_mfma_f32_16x16x32_bf16(af[ks], b, acc[j], 0, 0, 0);
    }
#pragma unroll
  for (int j = 0; j < 6; ++j) {
    int col = (wave * 6 + j) * 16 + ci;
    float bv = BF2F(bih[col]);
#pragma unroll
    for (int r = 0; r < 4; ++r)
      gi[(size_t)(row0 + quad * 4 + r) * 384 + col] = __float2bfloat16(acc[j][r] + bv);
  }
}

// ---------------------------------------------------------------------------
// kStep v2: 1024 blocks x 32 rows. wave&1 = row half (16 rows),
// wave>>1 = nt half (2 col-tiles); acc 6 tiles.
__global__ __launch_bounds__(256, 4) void kStep(
    const bf* __restrict__ Hp, const bf* __restrict__ Whh,
    const bf* __restrict__ G, int gld,
    const bf* __restrict__ bhh,
    bf* __restrict__ Ho, float* __restrict__ HcopyF) {
  const int half = blockIdx.z;
  const int tid = threadIdx.x;
  const int wave = tid >> 6, lane = tid & 63;
  const int quad = lane >> 4, ci = lane & 15;
  const int mr = blockIdx.x * 32 + (wave & 1) * 16;
  const int nt0 = (wave >> 1) * 2;

  float4v acc[6];
#pragma unroll
  for (int i = 0; i < 6; ++i) acc[i] = {0.f, 0.f, 0.f, 0.f};

#pragma unroll
  for (int ks = 0; ks < 4; ++ks) {
    short8 a = *(const short8*)(Hp + (size_t)(mr + ci) * 128 + ks * 32 + quad * 8);
#pragma unroll
    for (int g = 0; g < 3; ++g)
#pragma unroll
      for (int nt = 0; nt < 2; ++nt) {
        short8 b = *(const short8*)(Whh + (size_t)(g * 128 + half * 64 + (nt0 + nt) * 16 + ci) * 128 + ks * 32 + quad * 8);
        acc[g * 2 + nt] = __builtin_amdgcn_mfma_f32_16x16x32_bf16(a, b, acc[g * 2 + nt], 0, 0, 0);
      }
  }

  float bR[2], bZ[2], bN[2];
#pragma unroll
  for (int nt = 0; nt < 2; ++nt) {
    int c = half * 64 + (nt0 + nt) * 16 + ci;
    bR[nt] = BF2F(bhh[c]);
    bZ[nt] = BF2F(bhh[128 + c]);
    bN[nt] = BF2F(bhh[256 + c]);
  }

#pragma unroll
  for (int r = 0; r < 4; ++r) {
    int rr = mr + quad * 4 + r;
    const bf* gs = G + (size_t)rr * gld;
#pragma unroll
    for (int nt = 0; nt < 2; ++nt) {
      int c = half * 64 + (nt0 + nt) * 16 + ci;
      float gr = BF2F(gs[c]), gz = BF2F(gs[128 + c]), gnn = BF2F(gs[256 + c]);
      float pre_r = acc[nt][r] + gr + bR[nt];
      float pre_z = acc[2 + nt][r] + gz + bZ[nt];
      float hn_   = acc[4 + nt][r] + bN[nt];
      float rg = fsigmoid(pre_r);
      float zg = fsigmoid(pre_z);
      float ng = ftanh(gnn + rg * hn_);
      float hp = BF2F(Hp[(size_t)rr * 128 + c]);
      float hv = ng + zg * (hp - ng);
      Ho[(size_t)rr * 128 + c] = __float2bfloat16(hv);
      if (HcopyF) HcopyF[(size_t)rr * 128 + c] = hv;
    }
  }
}

// ---------------------------------------------------------------------------
// kSeq v7 (unchanged from R13): grid (1024, 2), 512 thr = 8 waves.
__global__ __launch_bounds__(512, 4) void kSeq(
    const bf* __restrict__ hrnn,
    const bf* __restrict__ Wih_f, const bf* __restrict__ Wih_b,
    const bf* __restrict__ Whh_f, const bf* __restrict__ Whh_b,
    const bf* __restrict__ bih_f, const bf* __restrict__ bih_b,
    const bf* __restrict__ bhh_f, const bf* __restrict__ bhh_b,
    const bf* __restrict__ Wcb, float* __restrict__ L) {
  __shared__ float sGiN[16][3][132];            // [batch][gate][hcol] fp32 25.3KB
  __shared__ bf sH[2][16][136];                 // h ping-pong [batch][hcol]
  __shared__ float sL[16][15][2];               // logits [batch][m][logit]
  __shared__ bf sWc[2][136];                    // Wc rows for this dir

  const int env = blockIdx.x;
  const int dir = blockIdx.y;
  const int tid = threadIdx.x;
  const int wave = tid >> 6, lane = tid & 63;
  const int nh = wave;
  const int quad = lane >> 4, ci = lane & 15;
  const bf* Wih = dir ? Wih_b : Wih_f;
  const bf* Whh = dir ? Whh_b : Whh_f;
  const bf* bih = dir ? bih_b : bih_f;
  const bf* bhh = dir ? bhh_b : bhh_f;
  const int h0q = nh * 16 + quad * 4;

  // ---- Phase 1: gi GEMM (swapped: D[hcol][batch]) ----
  float4v gS[3], gN[3];
#pragma unroll
  for (int i = 0; i < 3; ++i) { gS[i] = {0.f, 0.f, 0.f, 0.f}; gN[i] = {0.f, 0.f, 0.f, 0.f}; }
#pragma unroll
  for (int ks = 0; ks < 4; ++ks) {
    short8 bh = *(const short8*)(hrnn + (size_t)(env * 16 + ci) * 128 + ks * 32 + quad * 8);
#pragma unroll
    for (int g = 0; g < 3; ++g) {
      const bf* wrow = Wih + (size_t)(g * 128 + nh * 16 + ci) * 256 + ks * 32 + quad * 8;
      short8 ws = *(const short8*)(wrow);
      short8 wn = *(const short8*)(wrow + 128);
      gS[g] = __builtin_amdgcn_mfma_f32_16x16x32_bf16(ws, bh, gS[g], 0, 0, 0);
      gN[g] = __builtin_amdgcn_mfma_f32_16x16x32_bf16(wn, bh, gN[g], 0, 0, 0);
    }
  }
#pragma unroll
  for (int g = 0; g < 3; ++g)
#pragma unroll
    for (int r = 0; r < 4; ++r) {
      int c = g * 128 + h0q + r;
      float bv = BF2F(bih[c]);
      if (g < 2) bv += BF2F(bhh[c]);
      gS[g][r] += bv;
    }
  // nbr-gi straight to LDS as fp32 (one b128 store per gate)
#pragma unroll
  for (int g = 0; g < 3; ++g)
    *(float4v*)&sGiN[ci][g][h0q] = gN[g];

  {
    bf z = __float2bfloat16(0.f);
    bf* p = &sH[0][0][0];
    for (int i = tid; i < 16 * 136; i += 512) p[i] = z;
    if (tid < 256)
      sWc[tid >> 7][tid & 127] = Wcb[(dir * 2 + (tid >> 7)) * 128 + (tid & 127)];
  }

  // ---- Phase 2: persistent Whh A-frags, constants ----
  short8 Bf[12];
#pragma unroll
  for (int g = 0; g < 3; ++g)
#pragma unroll
    for (int ks = 0; ks < 4; ++ks)
      Bf[g * 4 + ks] =
          *(const short8*)(Whh + (size_t)(g * 128 + nh * 16 + ci) * 128 + ks * 32 + quad * 8);

  float bNc[4];
#pragma unroll
  for (int r = 0; r < 4; ++r) bNc[r] = BF2F(bhh[256 + h0q + r]);

  float hPrev[4];
#pragma unroll
  for (int r = 0; r < 4; ++r) hPrev[r] = 0.f;

  __syncthreads();

  // ---- Phase 3: 15 steps ----
  for (int t = 0; t < 15; ++t) {
    const int cur = t & 1, nxt = cur ^ 1;
    const int m = dir ? (14 - t) : t;
    const int jr = m + ((m >= ci) ? 1 : 0);

    float4v nbR = *(const float4v*)&sGiN[jr][0][h0q];
    float4v nbZ = *(const float4v*)&sGiN[jr][1][h0q];
    float4v nbN = *(const float4v*)&sGiN[jr][2][h0q];

    float4v acc[3];
#pragma unroll
    for (int i = 0; i < 3; ++i) acc[i] = {0.f, 0.f, 0.f, 0.f};
    float4v lacc = {0.f, 0.f, 0.f, 0.f};
#pragma unroll
    for (int ks = 0; ks < 4; ++ks) {
      short8 bh = *(const short8*)&sH[cur][ci][ks * 32 + quad * 8];
#pragma unroll
      for (int g = 0; g < 3; ++g)
        acc[g] = __builtin_amdgcn_mfma_f32_16x16x32_bf16(Bf[g * 4 + ks], bh, acc[g], 0, 0, 0);
      if (nh == 0) {
        short8 wv = *(const short8*)&sWc[ci & 1][ks * 32 + quad * 8];
        lacc = __builtin_amdgcn_mfma_f32_16x16x32_bf16(wv, bh, lacc, 0, 0, 0);
      }
    }
    if (nh == 0 && t > 0 && quad == 0) {
      int mp = dir ? (15 - t) : (t - 1);
      sL[ci][mp][0] = lacc[0];
      sL[ci][mp][1] = lacc[1];
    }

    short4v hv4;
#pragma unroll
    for (int r = 0; r < 4; ++r) {
      float pre_r = acc[0][r] + gS[0][r] + nbR[r];
      float pre_z = acc[1][r] + gS[1][r] + nbZ[r];
      float gnn   = gS[2][r] + nbN[r];
      float hn_   = acc[2][r] + bNc[r];
      float rg = fsigmoid(pre_r);
      float zg = fsigmoid(pre_z);
      float ng = ftanh(gnn + rg * hn_);
      float hv = ng + zg * (hPrev[r] - ng);
      hPrev[r] = hv;
      bf b = __float2bfloat16(hv);
      hv4[r] = *(short*)&b;
    }
    *(short4v*)&sH[nxt][ci][h0q] = hv4;
    __syncthreads();
  }

  if (nh == 0) {
    float4v lacc = {0.f, 0.f, 0.f, 0.f};
#pragma unroll
    for (int ks = 0; ks < 4; ++ks) {
      short8 bh = *(const short8*)&sH[1][ci][ks * 32 + quad * 8];
      short8 wv = *(const short8*)&sWc[ci & 1][ks * 32 + quad * 8];
      lacc = __builtin_amdgcn_mfma_f32_16x16x32_bf16(wv, bh, lacc, 0, 0, 0);
    }
    if (quad == 0) {
      int mf = dir ? 0 : 14;
      sL[ci][mf][0] = lacc[0];
      sL[ci][mf][1] = lacc[1];
    }
  }
  __syncthreads();

  {
    float* Ld = L + (size_t)dir * 491520 + (size_t)env * 480;
    for (int i = tid; i < 480; i += 512) {
      int row = i / 30, rem = i - row * 30;
      int mm = rem >> 1, l = rem & 1;
      Ld[i] = sL[row][mm][l];
    }
  }
}

// ---------------------------------------------------------------------------
// kTail v2: 1024 blocks x 1 env. qk MFMA + gumbel + attn -> sAgg (LDS),
// then out14 GEMM (wave 0) for this env's 16 rows.
__global__ __launch_bounds__(256) void kTail(
    const bf* __restrict__ h, const bf* __restrict__ Wqk,
    const float* __restrict__ L, const void* __restrict__ guRaw,
    const void* __restrict__ bcRaw, const int* __restrict__ flag,
    const bf* __restrict__ W2p, const void* __restrict__ b2Raw,
    float* __restrict__ out) {
  __shared__ float sh[16 * 132];
  __shared__ float sqk[16 * 64];
  __shared__ float shw[240];
  __shared__ float sw[16 * 16];
  __shared__ bf sAgg[16][136];
  const int bb = blockIdx.x;
  const int tid = threadIdx.x;
  const int f = *flag;
  const int a = tid >> 4, i = tid & 15;

  {
    const int w = tid >> 6, lane = tid & 63;
    const int quad = lane >> 4, ci = lane & 15;
    float4v acc = {0.f, 0.f, 0.f, 0.f};
#pragma unroll
    for (int ks = 0; ks < 4; ++ks) {
      short8 a_ = *(const short8*)(h + (size_t)(bb * 16 + ci) * 128 + ks * 32 + quad * 8);
      short8 b_ = *(const short8*)(Wqk + (size_t)(w * 16 + ci) * 128 + ks * 32 + quad * 8);
      acc = __builtin_amdgcn_mfma_f32_16x16x32_bf16(a_, b_, acc, 0, 0, 0);
    }
#pragma unroll
    for (int r = 0; r < 4; ++r)
      sqk[(quad * 4 + r) * 64 + w * 16 + ci] = acc[r];
  }
  for (int k = tid; k < 2048; k += 256)
    sh[(k >> 7) * 132 + (k & 127)] = BF2F(h[(size_t)bb * 2048 + k]);
  if (tid < 240) {
    int idx = bb * 240 + tid;
    float l0 = L[(size_t)idx * 2]     + L[491520 + (size_t)idx * 2]     + rdv(bcRaw, 0, f);
    float l1 = L[(size_t)idx * 2 + 1] + L[491520 + (size_t)idx * 2 + 1] + rdv(bcRaw, 1, f);
    float u0 = rdv(guRaw, idx * 2, f);
    float u1 = rdv(guRaw, idx * 2 + 1, f);
    float g0 = -__logf(-__logf(u0 + 1e-10f) + 1e-10f);
    float g1 = -__logf(-__logf(u1 + 1e-10f) + 1e-10f);
    shw[tid] = fsigmoid(((l1 + g1) - (l0 + g0)) * 2.0f);
  }
  __syncthreads();

  float s = -1e30f;
  if (i < 15) {
    int j = i + (i >= a);
    float d = 0.f;
#pragma unroll
    for (int c = 0; c < 32; ++c) d += sqk[a * 64 + c] * sqk[j * 64 + 32 + c];
    s = shw[a * 15 + i] * d * 0.17677669529663687f;
  }
  float mx = s;
#pragma unroll
  for (int d = 1; d < 16; d <<= 1) mx = fmaxf(mx, __shfl_xor(mx, d));
  float ex = (i < 15) ? __expf(s - mx) : 0.f;
  float sum = ex;
#pragma unroll
  for (int d = 1; d < 16; d <<= 1) sum += __shfl_xor(sum, d);
  float w = (i < 15) ? (ex * frcp(sum)) * shw[a * 15 + i] : 0.f;
  sw[a * 16 + i] = w;
  __syncthreads();

  float ac[8] = {0, 0, 0, 0, 0, 0, 0, 0};
  for (int mm = 0; mm < 15; ++mm) {
    int jm = mm + (mm >= a);
    float wm = sw[a * 16 + mm];
    const float* shp = &sh[jm * 132 + i * 8];
    float4 h0 = *(const float4*)shp;
    float4 h1 = *(const float4*)(shp + 4);
    ac[0] += wm * h0.x; ac[1] += wm * h0.y; ac[2] += wm * h0.z; ac[3] += wm * h0.w;
    ac[4] += wm * h1.x; ac[5] += wm * h1.y; ac[6] += wm * h1.z; ac[7] += wm * h1.w;
  }
  short8 v;
#pragma unroll
  for (int d = 0; d < 8; ++d) {
    bf b = __float2bfloat16(ac[d]);
    v[d] = *(short*)&b;
  }
  *(short8*)&sAgg[a][i * 8] = v;
  __syncthreads();

  // out14 GEMM for this env's 16 rows (wave 0)
  if (tid < 64) {
    const int quad = tid >> 4, ci = tid & 15;
    const int mr = bb * 16;
    float4v acc = {0.f, 0.f, 0.f, 0.f};
#pragma unroll
    for (int ks = 0; ks < 4; ++ks) {
      short8 a_ = *(const short8*)(h + (size_t)(mr + ci) * 128 + ks * 32 + quad * 8);
      short8 b_ = *(const short8*)(W2p + (size_t)ci * 256 + ks * 32 + quad * 8);
      acc = __builtin_amdgcn_mfma_f32_16x16x32_bf16(a_, b_, acc, 0, 0, 0);
    }
#pragma unroll
    for (int ks = 0; ks < 4; ++ks) {
      short8 a_ = *(const short8*)&sAgg[ci][ks * 32 + quad * 8];
      short8 b_ = *(const short8*)(W2p + (size_t)ci * 256 + 128 + ks * 32 + quad * 8);
      acc = __builtin_amdgcn_mfma_f32_16x16x32_bf16(a_, b_, acc, 0, 0, 0);
    }
    if (ci < 14) {
      float bv = rdv(b2Raw, ci, f);
#pragma unroll
      for (int r = 0; r < 4; ++r)
        out[(size_t)(mr + quad * 4 + r) * 14 + ci] = acc[r] + bv;
    }
  }
}

// ---------------------------------------------------------------------------
extern "C" void kernel_launch(void* const* d_in, const int* in_sizes, int n_in,
                              void* d_out, int out_size, void* d_ws, size_t ws_size,
                              hipStream_t stream) {
  const size_t OFF_ARENA = 0;          // bf16 arena; L (3.93MB) overlaps dead
                                       //   inputs+hidden [0, 8.38MB) after cell
  const size_t OFF_FLAG  = 10220544;
  const size_t OFF_A     = 10220800;   // gi_c
  const size_t OFF_WQK   = 26998016;   // 16 KB
  const size_t OFF_WCB   = 27014400;   // 1 KB
  const size_t OFF_W2P   = 27410944;   // 8 KB
  const size_t OFF_HRNN  = 27419136;   // 4 MB
  const size_t NEEDED    = 84042240;
  if (ws_size < NEEDED) return;
  if (n_in < 23 || in_sizes[0] != 2097152 || in_sizes[3] != 16384 ||
      in_sizes[5] != 49152 || in_sizes[9] != 98304 || in_sizes[17] != 512 ||
      in_sizes[19] != 4096 || in_sizes[21] != 3584 || out_size != 2326528)
    return;

  char* ws = (char*)d_ws;
  bf*    arena = (bf*)(ws + OFF_ARENA);
  float* L     = (float*)(ws + OFF_ARENA);  // 3.93 MB; valid after cell GRU
  int*   flag  = (int*)(ws + OFF_FLAG);
  bf*    gi_c  = (bf*)(ws + OFF_A + 4194304);
  bf*    Wqk   = (bf*)(ws + OFF_WQK);
  bf*    Wcb   = (bf*)(ws + OFF_WCB);
  bf*    W2p   = (bf*)(ws + OFF_W2P);
  bf*    hrnn  = (bf*)(ws + OFF_HRNN);

  float* out14 = (float*)d_out;
  float* outh  = (float*)d_out + 229376;

  CArgs ca;
  for (int i = 0; i < 23; ++i) { ca.src[i] = d_in[i]; ca.n[i] = AN[i]; ca.off[i] = AO[i]; }
  kConvert<<<dim3(128, 24), 256, 0, stream>>>(ca, flag, arena,
                                              d_in[19], d_in[20], d_in[21], d_in[17],
                                              Wqk, W2p, Wcb);

  const bf* inputs = arena + AO[0];
  const bf* hidden = arena + AO[1];
  const bf* W1     = arena + AO[3];
  const bf* b1     = arena + AO[4];
  const bf* Wih_c  = arena + AO[5];
  const bf* Whh_c  = arena + AO[6];
  const bf* bih_c  = arena + AO[7];
  const bf* bhh_c  = arena + AO[8];
  const bf* Wih_f  = arena + AO[9];
  const bf* Whh_f  = arena + AO[10];
  const bf* bih_f  = arena + AO[11];
  const bf* bhh_f  = arena + AO[12];
  const bf* Wih_b  = arena + AO[13];
  const bf* Whh_b  = arena + AO[14];
  const bf* bih_b  = arena + AO[15];
  const bf* bhh_b  = arena + AO[16];

  // fused x1 + gi_c (1024 blocks, 4/CU)
  kFused12<<<dim3(1024), 256, 0, stream>>>(inputs, W1, b1, Wih_c, bih_c, gi_c);
  // cell GRU: h_rnn (bf16 + fp32 copy to d_out) (1024 blocks)
  kStep<<<dim3(512, 1, 2), 256, 0, stream>>>(hidden, Whh_c, gi_c, 384, bhh_c,
                                             hrnn, outh);
  // fused gi-GEMM + 15-step bidirectional GRU -> L (2 dir planes)
  kSeq<<<dim3(1024, 2), 512, 0, stream>>>(hrnn, Wih_f, Wih_b, Whh_f, Whh_b,
                                          bih_f, bih_b, bhh_f, bhh_b, Wcb, L);
  // fused qk + gumbel + attention + out14 GEMM (1024 blocks)
  kTail<<<dim3(1024), 256, 0, stream>>>(hrnn, Wqk, L, d_in[2], d_in[18], flag,
                                        W2p, d_in[22], out14);
}

// Round 7
// 264.622 us; speedup vs baseline: 1.0607x; 1.0106x over previous
//
#include <hip/hip_runtime.h>
#include <hip/hip_bf16.h>

// G2AAgent — ROUND 15: kSeq C-init diet + kPre fusion (5 -> 4 dispatches).
//  R14 post-mortem: re-grid saved ~10us; non-kSeq floor ~148us vs ~30us
//  bottom-up kernel estimate -> ~120us fixed harness/dispatch overhead
//  hypothesis. kSeq counter arithmetic: VALUBusy 51% = ~608 cyc/wave-step;
//  hand count closes only when v_exp/v_rcp are priced quarter-rate (8cyc
//  wave64): 24 trans/thread-step = ~192cyc. Trans count irreducible (3
//  sigmoid/tanh per elem); regular-VALU fat is not. This round:
//   (a) kSeq v8: MFMA C-init = gS/bNc (first MFMA carries input-gate sums)
//       -> -16 epilogue adds/thread-step; sum reorder = ULP-level only.
//   (b) kPre: fuse x1+gi+cellGRU env-locally (replaces kFused12+kStep);
//       gi stays fp32 in regs (skips bf16 round + 25MB traffic). Same MFMA
//       count (224/env), same formulas.
//  Attribution: kSeq delta = (a) via counters; total-minus-kSeq delta = (b).
//  Decision rule: non-kSeq drop >=10us -> mega-fusion next; <5us -> floor
//  is fixed overhead.

typedef __attribute__((ext_vector_type(8))) short short8;
typedef __attribute__((ext_vector_type(4))) short short4v;
typedef __attribute__((ext_vector_type(4))) float float4v;

#define BF2F(x) __bfloat162float(x)
typedef __hip_bfloat16 bf;

__device__ __forceinline__ float frcp(float x) {
  return __builtin_amdgcn_rcpf(x);
}
__device__ __forceinline__ float fsigmoid(float x) {
  return frcp(1.f + __expf(-x));
}
__device__ __forceinline__ float ftanh(float x) {
  float e = __expf(2.f * x);
  return 1.f - 2.f * frcp(1.f + e);
}
__device__ __forceinline__ float rdv(const void* p, int i, int f) {
  return f ? ((const float*)p)[i] : BF2F(((const bf*)p)[i]);
}

// ---------------------------------------------------------------------------
static const int AO[23] = {
  0, 2097152, 4194304, 4685824, 4702208, 4702336, 4751488, 4800640, 4801024,
  4801408, 4899712, 4948864, 4949248, 4949632, 5047936, 5097088, 5097472,
  5097856, 5098368, 5098384, 5102480, 5106576, 5110160};
static const int AN[23] = {
  2097152, 2097152, 491520, 16384, 128, 49152, 49152, 384, 384, 98304, 49152,
  384, 384, 98304, 49152, 384, 384, 512, 2, 4096, 4096, 3584, 14};

struct CArgs {
  const void* src[23];
  int n[23];
  int off[23];
};

// ---------------------------------------------------------------------------
// kConvert: per-block self-detect of input dtype; y<23 = vectorized
// normalize into arena (skips 2/18/22); y==23 = prep (Wqk/W2p/Wcb).
__global__ void kConvert(CArgs a, int* __restrict__ flagOut,
                         bf* __restrict__ arena,
                         const void* __restrict__ WqR, const void* __restrict__ WkR,
                         const void* __restrict__ W2R, const void* __restrict__ WcR,
                         bf* __restrict__ Wqk, bf* __restrict__ W2p,
                         bf* __restrict__ Wcb) {
  __shared__ int sflag;
  if (threadIdx.x == 0) sflag = 0;
  __syncthreads();
  {
    const unsigned short* p0 = (const unsigned short*)a.src[0];
    int hit = 0;
    for (int i = threadIdx.x; i < 4096; i += 256) {
      int e = (p0[i] >> 7) & 0xFF;
      if (e >= 0xC0) hit = 1;
    }
    if (hit) atomicOr(&sflag, 1);
  }
  __syncthreads();
  const int f = sflag;
  const int b = blockIdx.y;
  if (b == 0 && blockIdx.x == 0 && threadIdx.x == 0) *flagOut = f;

  if (b == 23) {  // prep
    int idx = blockIdx.x * 256 + threadIdx.x;
    if (idx < 8192) {
      int r = idx >> 7, c = idx & 127;
      float v = (r < 32) ? rdv(WqR, r * 128 + c, f) : rdv(WkR, (r - 32) * 128 + c, f);
      Wqk[idx] = __float2bfloat16(v);
    }
    if (idx < 4096)
      W2p[idx] = __float2bfloat16((idx < 3584) ? rdv(W2R, idx, f) : 0.f);
    if (idx < 512) {
      int dir = idx >> 8, l = (idx >> 7) & 1, k = idx & 127;
      Wcb[idx] = __float2bfloat16(rdv(WcR, l * 256 + dir * 128 + k, f));
    }
    return;
  }
  if (b == 2 || b == 18 || b == 22) return;  // consumed raw via rdv
  const int n = a.n[b];
  const int nv = n & ~7;
  bf* dst = arena + a.off[b];
  const int gid = blockIdx.x * 256 + threadIdx.x;
  const int gs = gridDim.x * 256;
  if (f) {
    const float* s = (const float*)a.src[b];
    for (int i = gid * 8; i < nv; i += gs * 8) {
      float4 x0 = *(const float4*)(s + i);
      float4 x1 = *(const float4*)(s + i + 4);
      short8 v;
      bf t;
      t = __float2bfloat16(x0.x); v[0] = *(short*)&t;
      t = __float2bfloat16(x0.y); v[1] = *(short*)&t;
      t = __float2bfloat16(x0.z); v[2] = *(short*)&t;
      t = __float2bfloat16(x0.w); v[3] = *(short*)&t;
      t = __float2bfloat16(x1.x); v[4] = *(short*)&t;
      t = __float2bfloat16(x1.y); v[5] = *(short*)&t;
      t = __float2bfloat16(x1.z); v[6] = *(short*)&t;
      t = __float2bfloat16(x1.w); v[7] = *(short*)&t;
      *(short8*)(dst + i) = v;
    }
    for (int i = nv + gid; i < n; i += gs) dst[i] = __float2bfloat16(s[i]);
  } else {
    const short8* s = (const short8*)a.src[b];
    short8* d = (short8*)dst;
    for (int i = gid; i * 8 < nv; i += gs) d[i] = s[i];
    const unsigned short* ss = (const unsigned short*)a.src[b];
    unsigned short* ds = (unsigned short*)dst;
    for (int i = nv + gid; i < n; i += gs) ds[i] = ss[i];
  }
}

// ---------------------------------------------------------------------------
// kPre: env-local fusion of x1 + gi_c + cell GRU. 1024 blocks x 16 rows.
// Stage A: x1 swapped MFMA (4 waves x 2 col-tiles) -> sX (bf16, LDS).
// Stage B: gh = Hp@Whh^T and gi = x1@Wih^T, standard layout, wave owns a
// 32-col slice x 3 gates (12 MFMA each). Epilogue: GRU cell in fp32 regs
// (gi never rounded to bf16 or written to global). Writes hrnn + outh.
__global__ __launch_bounds__(256) void kPre(
    const bf* __restrict__ inputs, const bf* __restrict__ W1,
    const bf* __restrict__ b1, const bf* __restrict__ Wih,
    const bf* __restrict__ bih, const bf* __restrict__ hidden,
    const bf* __restrict__ Whh, const bf* __restrict__ bhh,
    bf* __restrict__ hrnn, float* __restrict__ outh) {
  __shared__ bf sX[16][136];  // x1 tile, 4.25 KB
  const int tid = threadIdx.x;
  const int wave = tid >> 6, lane = tid & 63;
  const int quad = lane >> 4, ci = lane & 15;
  const int row0 = blockIdx.x * 16;

  // stage A: swapped -> D[x1col][row]; wave owns col-tiles {2w, 2w+1}.
  float4v xa[2];
#pragma unroll
  for (int i = 0; i < 2; ++i) xa[i] = {0.f, 0.f, 0.f, 0.f};
#pragma unroll
  for (int ks = 0; ks < 4; ++ks) {
    short8 inr = *(const short8*)(inputs + (size_t)(row0 + ci) * 128 + ks * 32 + quad * 8);
#pragma unroll
    for (int c2 = 0; c2 < 2; ++c2) {
      int ct = wave * 2 + c2;
      short8 wfr = *(const short8*)(W1 + (size_t)(ct * 16 + ci) * 128 + ks * 32 + quad * 8);
      xa[c2] = __builtin_amdgcn_mfma_f32_16x16x32_bf16(wfr, inr, xa[c2], 0, 0, 0);
    }
  }
#pragma unroll
  for (int c2 = 0; c2 < 2; ++c2) {
    int ct = wave * 2 + c2;
    short4v v4;
#pragma unroll
    for (int r = 0; r < 4; ++r) {
      float v = xa[c2][r] + BF2F(b1[ct * 16 + quad * 4 + r]);
      v = fmaxf(v, 0.f);
      bf t = __float2bfloat16(v);
      v4[r] = *(short*)&t;
    }
    *(short4v*)&sX[ci][ct * 16 + quad * 4] = v4;
  }
  __syncthreads();

  short8 af[4];
#pragma unroll
  for (int ks = 0; ks < 4; ++ks)
    af[ks] = *(const short8*)&sX[ci][ks * 32 + quad * 8];

  // stage B: gh + gi, standard D[row][col]; wave owns cols wave*32 + nt*16.
  float4v ah[6], ag[6];
#pragma unroll
  for (int i = 0; i < 6; ++i) { ah[i] = {0.f, 0.f, 0.f, 0.f}; ag[i] = {0.f, 0.f, 0.f, 0.f}; }
#pragma unroll
  for (int ks = 0; ks < 4; ++ks) {
    short8 hr = *(const short8*)(hidden + (size_t)(row0 + ci) * 128 + ks * 32 + quad * 8);
#pragma unroll
    for (int g = 0; g < 3; ++g)
#pragma unroll
      for (int nt = 0; nt < 2; ++nt) {
        int wrow = g * 128 + wave * 32 + nt * 16 + ci;
        short8 bw = *(const short8*)(Whh + (size_t)wrow * 128 + ks * 32 + quad * 8);
        ah[g * 2 + nt] = __builtin_amdgcn_mfma_f32_16x16x32_bf16(hr, bw, ah[g * 2 + nt], 0, 0, 0);
        short8 bi_ = *(const short8*)(Wih + (size_t)wrow * 128 + ks * 32 + quad * 8);
        ag[g * 2 + nt] = __builtin_amdgcn_mfma_f32_16x16x32_bf16(af[ks], bi_, ag[g * 2 + nt], 0, 0, 0);
      }
  }

#pragma unroll
  for (int nt = 0; nt < 2; ++nt) {
    int c = wave * 32 + nt * 16 + ci;
    float biR = BF2F(bih[c]),       bhR = BF2F(bhh[c]);
    float biZ = BF2F(bih[128 + c]), bhZ = BF2F(bhh[128 + c]);
    float biN = BF2F(bih[256 + c]), bhN = BF2F(bhh[256 + c]);
#pragma unroll
    for (int r = 0; r < 4; ++r) {
      int rr = row0 + quad * 4 + r;
      float pre_r = ah[nt][r] + (ag[nt][r] + biR) + bhR;
      float pre_z = ah[2 + nt][r] + (ag[2 + nt][r] + biZ) + bhZ;
      float gnn   = ag[4 + nt][r] + biN;
      float hn_   = ah[4 + nt][r] + bhN;
      float rg = fsigmoid(pre_r);
      float zg = fsigmoid(pre_z);
      float ng = ftanh(gnn + rg * hn_);
      float hp = BF2F(hidden[(size_t)rr * 128 + c]);
      float hv = ng + zg * (hp - ng);
      hrnn[(size_t)rr * 128 + c] = __float2bfloat16(hv);
      outh[(size_t)rr * 128 + c] = hv;
    }
  }
}

// ---------------------------------------------------------------------------
// kSeq v8: grid (1024, 2), 512 thr = 8 waves. Operand-swapped MFMAs;
// fp32 nbr-gi; C-INIT: acc[0]=gS[0], acc[1]=gS[1], acc[2]=bNcV so the
// MFMA chain carries the input-gate sums (-16 epilogue adds/thread-step).
__global__ __launch_bounds__(512, 4) void kSeq(
    const bf* __restrict__ hrnn,
    const bf* __restrict__ Wih_f, const bf* __restrict__ Wih_b,
    const bf* __restrict__ Whh_f, const bf* __restrict__ Whh_b,
    const bf* __restrict__ bih_f, const bf* __restrict__ bih_b,
    const bf* __restrict__ bhh_f, const bf* __restrict__ bhh_b,
    const bf* __restrict__ Wcb, float* __restrict__ L) {
  __shared__ float sGiN[16][3][132];            // [batch][gate][hcol] fp32 25.3KB
  __shared__ bf sH[2][16][136];                 // h ping-pong [batch][hcol]
  __shared__ float sL[16][15][2];               // logits [batch][m][logit]
  __shared__ bf sWc[2][136];                    // Wc rows for this dir

  const int env = blockIdx.x;
  const int dir = blockIdx.y;
  const int tid = threadIdx.x;
  const int wave = tid >> 6, lane = tid & 63;
  const int nh = wave;
  const int quad = lane >> 4, ci = lane & 15;
  const bf* Wih = dir ? Wih_b : Wih_f;
  const bf* Whh = dir ? Whh_b : Whh_f;
  const bf* bih = dir ? bih_b : bih_f;
  const bf* bhh = dir ? bhh_b : bhh_f;
  const int h0q = nh * 16 + quad * 4;

  // ---- Phase 1: gi GEMM (swapped: D[hcol][batch]) ----
  float4v gS[3], gN[3];
#pragma unroll
  for (int i = 0; i < 3; ++i) { gS[i] = {0.f, 0.f, 0.f, 0.f}; gN[i] = {0.f, 0.f, 0.f, 0.f}; }
#pragma unroll
  for (int ks = 0; ks < 4; ++ks) {
    short8 bh = *(const short8*)(hrnn + (size_t)(env * 16 + ci) * 128 + ks * 32 + quad * 8);
#pragma unroll
    for (int g = 0; g < 3; ++g) {
      const bf* wrow = Wih + (size_t)(g * 128 + nh * 16 + ci) * 256 + ks * 32 + quad * 8;
      short8 ws = *(const short8*)(wrow);
      short8 wn = *(const short8*)(wrow + 128);
      gS[g] = __builtin_amdgcn_mfma_f32_16x16x32_bf16(ws, bh, gS[g], 0, 0, 0);
      gN[g] = __builtin_amdgcn_mfma_f32_16x16x32_bf16(wn, bh, gN[g], 0, 0, 0);
    }
  }
#pragma unroll
  for (int g = 0; g < 3; ++g)
#pragma unroll
    for (int r = 0; r < 4; ++r) {
      int c = g * 128 + h0q + r;
      float bv = BF2F(bih[c]);
      if (g < 2) bv += BF2F(bhh[c]);
      gS[g][r] += bv;
    }
  // nbr-gi straight to LDS as fp32 (one b128 store per gate)
#pragma unroll
  for (int g = 0; g < 3; ++g)
    *(float4v*)&sGiN[ci][g][h0q] = gN[g];

  {
    bf z = __float2bfloat16(0.f);
    bf* p = &sH[0][0][0];
    for (int i = tid; i < 16 * 136; i += 512) p[i] = z;
    if (tid < 256)
      sWc[tid >> 7][tid & 127] = Wcb[(dir * 2 + (tid >> 7)) * 128 + (tid & 127)];
  }

  // ---- Phase 2: persistent Whh A-frags, constants ----
  short8 Bf[12];
#pragma unroll
  for (int g = 0; g < 3; ++g)
#pragma unroll
    for (int ks = 0; ks < 4; ++ks)
      Bf[g * 4 + ks] =
          *(const short8*)(Whh + (size_t)(g * 128 + nh * 16 + ci) * 128 + ks * 32 + quad * 8);

  float4v bNcV;
#pragma unroll
  for (int r = 0; r < 4; ++r) bNcV[r] = BF2F(bhh[256 + h0q + r]);

  float hPrev[4];
#pragma unroll
  for (int r = 0; r < 4; ++r) hPrev[r] = 0.f;

  __syncthreads();

  // ---- Phase 3: 15 steps ----
  for (int t = 0; t < 15; ++t) {
    const int cur = t & 1, nxt = cur ^ 1;
    const int m = dir ? (14 - t) : t;
    const int jr = m + ((m >= ci) ? 1 : 0);

    float4v nbR = *(const float4v*)&sGiN[jr][0][h0q];
    float4v nbZ = *(const float4v*)&sGiN[jr][1][h0q];
    float4v nbN = *(const float4v*)&sGiN[jr][2][h0q];

    // C-init: MFMA chain carries gS (r,z) and bhh_n (hidden-n bias)
    float4v acc[3];
    acc[0] = gS[0];
    acc[1] = gS[1];
    acc[2] = bNcV;
    float4v lacc = {0.f, 0.f, 0.f, 0.f};
#pragma unroll
    for (int ks = 0; ks < 4; ++ks) {
      short8 bh = *(const short8*)&sH[cur][ci][ks * 32 + quad * 8];
#pragma unroll
      for (int g = 0; g < 3; ++g)
        acc[g] = __builtin_amdgcn_mfma_f32_16x16x32_bf16(Bf[g * 4 + ks], bh, acc[g], 0, 0, 0);
      if (nh == 0) {
        short8 wv = *(const short8*)&sWc[ci & 1][ks * 32 + quad * 8];
        lacc = __builtin_amdgcn_mfma_f32_16x16x32_bf16(wv, bh, lacc, 0, 0, 0);
      }
    }
    if (nh == 0 && t > 0 && quad == 0) {
      int mp = dir ? (15 - t) : (t - 1);
      sL[ci][mp][0] = lacc[0];
      sL[ci][mp][1] = lacc[1];
    }

    short4v hv4;
#pragma unroll
    for (int r = 0; r < 4; ++r) {
      float pre_r = acc[0][r] + nbR[r];
      float pre_z = acc[1][r] + nbZ[r];
      float gnn   = gS[2][r] + nbN[r];
      float hn_   = acc[2][r];
      float rg = fsigmoid(pre_r);
      float zg = fsigmoid(pre_z);
      float ng = ftanh(gnn + rg * hn_);
      float hv = ng + zg * (hPrev[r] - ng);
      hPrev[r] = hv;
      bf b = __float2bfloat16(hv);
      hv4[r] = *(short*)&b;
    }
    *(short4v*)&sH[nxt][ci][h0q] = hv4;
    __syncthreads();
  }

  if (nh == 0) {
    float4v lacc = {0.f, 0.f, 0.f, 0.f};
#pragma unroll
    for (int ks = 0; ks < 4; ++ks) {
      short8 bh = *(const short8*)&sH[1][ci][ks * 32 + quad * 8];
      short8 wv = *(const short8*)&sWc[ci & 1][ks * 32 + quad * 8];
      lacc = __builtin_amdgcn_mfma_f32_16x16x32_bf16(wv, bh, lacc, 0, 0, 0);
    }
    if (quad == 0) {
      int mf = dir ? 0 : 14;
      sL[ci][mf][0] = lacc[0];
      sL[ci][mf][1] = lacc[1];
    }
  }
  __syncthreads();

  {
    float* Ld = L + (size_t)dir * 491520 + (size_t)env * 480;
    for (int i = tid; i < 480; i += 512) {
      int row = i / 30, rem = i - row * 30;
      int mm = rem >> 1, l = rem & 1;
      Ld[i] = sL[row][mm][l];
    }
  }
}

// ---------------------------------------------------------------------------
// kTail: 1024 blocks x 1 env. qk MFMA + gumbel + attn -> sAgg (LDS),
// then out14 GEMM (wave 0) for this env's 16 rows.
__global__ __launch_bounds__(256) void kTail(
    const bf* __restrict__ h, const bf* __restrict__ Wqk,
    const float* __restrict__ L, const void* __restrict__ guRaw,
    const void* __restrict__ bcRaw, const int* __restrict__ flag,
    const bf* __restrict__ W2p, const void* __restrict__ b2Raw,
    float* __restrict__ out) {
  __shared__ float sh[16 * 132];
  __shared__ float sqk[16 * 64];
  __shared__ float shw[240];
  __shared__ float sw[16 * 16];
  __shared__ bf sAgg[16][136];
  const int bb = blockIdx.x;
  const int tid = threadIdx.x;
  const int f = *flag;
  const int a = tid >> 4, i = tid & 15;

  {
    const int w = tid >> 6, lane = tid & 63;
    const int quad = lane >> 4, ci = lane & 15;
    float4v acc = {0.f, 0.f, 0.f, 0.f};
#pragma unroll
    for (int ks = 0; ks < 4; ++ks) {
      short8 a_ = *(const short8*)(h + (size_t)(bb * 16 + ci) * 128 + ks * 32 + quad * 8);
      short8 b_ = *(const short8*)(Wqk + (size_t)(w * 16 + ci) * 128 + ks * 32 + quad * 8);
      acc = __builtin_amdgcn_mfma_f32_16x16x32_bf16(a_, b_, acc, 0, 0, 0);
    }
#pragma unroll
    for (int r = 0; r < 4; ++r)
      sqk[(quad * 4 + r) * 64 + w * 16 + ci] = acc[r];
  }
  for (int k = tid; k < 2048; k += 256)
    sh[(k >> 7) * 132 + (k & 127)] = BF2F(h[(size_t)bb * 2048 + k]);
  if (tid < 240) {
    int idx = bb * 240 + tid;
    float l0 = L[(size_t)idx * 2]     + L[491520 + (size_t)idx * 2]     + rdv(bcRaw, 0, f);
    float l1 = L[(size_t)idx * 2 + 1] + L[491520 + (size_t)idx * 2 + 1] + rdv(bcRaw, 1, f);
    float u0 = rdv(guRaw, idx * 2, f);
    float u1 = rdv(guRaw, idx * 2 + 1, f);
    float g0 = -__logf(-__logf(u0 + 1e-10f) + 1e-10f);
    float g1 = -__logf(-__logf(u1 + 1e-10f) + 1e-10f);
    shw[tid] = fsigmoid(((l1 + g1) - (l0 + g0)) * 2.0f);
  }
  __syncthreads();

  float s = -1e30f;
  if (i < 15) {
    int j = i + (i >= a);
    float d = 0.f;
#pragma unroll
    for (int c = 0; c < 32; ++c) d += sqk[a * 64 + c] * sqk[j * 64 + 32 + c];
    s = shw[a * 15 + i] * d * 0.17677669529663687f;
  }
  float mx = s;
#pragma unroll
  for (int d = 1; d < 16; d <<= 1) mx = fmaxf(mx, __shfl_xor(mx, d));
  float ex = (i < 15) ? __expf(s - mx) : 0.f;
  float sum = ex;
#pragma unroll
  for (int d = 1; d < 16; d <<= 1) sum += __shfl_xor(sum, d);
  float w = (i < 15) ? (ex * frcp(sum)) * shw[a * 15 + i] : 0.f;
  sw[a * 16 + i] = w;
  __syncthreads();

  float ac[8] = {0, 0, 0, 0, 0, 0, 0, 0};
  for (int mm = 0; mm < 15; ++mm) {
    int jm = mm + (mm >= a);
    float wm = sw[a * 16 + mm];
    const float* shp = &sh[jm * 132 + i * 8];
    float4 h0 = *(const float4*)shp;
    float4 h1 = *(const float4*)(shp + 4);
    ac[0] += wm * h0.x; ac[1] += wm * h0.y; ac[2] += wm * h0.z; ac[3] += wm * h0.w;
    ac[4] += wm * h1.x; ac[5] += wm * h1.y; ac[6] += wm * h1.z; ac[7] += wm * h1.w;
  }
  short8 v;
#pragma unroll
  for (int d = 0; d < 8; ++d) {
    bf b = __float2bfloat16(ac[d]);
    v[d] = *(short*)&b;
  }
  *(short8*)&sAgg[a][i * 8] = v;
  __syncthreads();

  // out14 GEMM for this env's 16 rows (wave 0)
  if (tid < 64) {
    const int quad = tid >> 4, ci = tid & 15;
    const int mr = bb * 16;
    float4v acc = {0.f, 0.f, 0.f, 0.f};
#pragma unroll
    for (int ks = 0; ks < 4; ++ks) {
      short8 a_ = *(const short8*)(h + (size_t)(mr + ci) * 128 + ks * 32 + quad * 8);
      short8 b_ = *(const short8*)(W2p + (size_t)ci * 256 + ks * 32 + quad * 8);
      acc = __builtin_amdgcn_mfma_f32_16x16x32_bf16(a_, b_, acc, 0, 0, 0);
    }
#pragma unroll
    for (int ks = 0; ks < 4; ++ks) {
      short8 a_ = *(const short8*)&sAgg[ci][ks * 32 + quad * 8];
      short8 b_ = *(const short8*)(W2p + (size_t)ci * 256 + 128 + ks * 32 + quad * 8);
      acc = __builtin_amdgcn_mfma_f32_16x16x32_bf16(a_, b_, acc, 0, 0, 0);
    }
    if (ci < 14) {
      float bv = rdv(b2Raw, ci, f);
#pragma unroll
      for (int r = 0; r < 4; ++r)
        out[(size_t)(mr + quad * 4 + r) * 14 + ci] = acc[r] + bv;
    }
  }
}

// ---------------------------------------------------------------------------
extern "C" void kernel_launch(void* const* d_in, const int* in_sizes, int n_in,
                              void* d_out, int out_size, void* d_ws, size_t ws_size,
                              hipStream_t stream) {
  const size_t OFF_ARENA = 0;          // bf16 arena; L (3.93MB) overlaps dead
                                       //   inputs+hidden [0, 8.38MB) after kPre
  const size_t OFF_FLAG  = 10220544;
  const size_t OFF_WQK   = 26998016;   // 16 KB
  const size_t OFF_WCB   = 27014400;   // 1 KB
  const size_t OFF_W2P   = 27410944;   // 8 KB
  const size_t OFF_HRNN  = 27419136;   // 4 MB
  const size_t NEEDED    = 84042240;
  if (ws_size < NEEDED) return;
  if (n_in < 23 || in_sizes[0] != 2097152 || in_sizes[3] != 16384 ||
      in_sizes[5] != 49152 || in_sizes[9] != 98304 || in_sizes[17] != 512 ||
      in_sizes[19] != 4096 || in_sizes[21] != 3584 || out_size != 2326528)
    return;

  char* ws = (char*)d_ws;
  bf*    arena = (bf*)(ws + OFF_ARENA);
  float* L     = (float*)(ws + OFF_ARENA);  // 3.93 MB; valid after kPre
  int*   flag  = (int*)(ws + OFF_FLAG);
  bf*    Wqk   = (bf*)(ws + OFF_WQK);
  bf*    Wcb   = (bf*)(ws + OFF_WCB);
  bf*    W2p   = (bf*)(ws + OFF_W2P);
  bf*    hrnn  = (bf*)(ws + OFF_HRNN);

  float* out14 = (float*)d_out;
  float* outh  = (float*)d_out + 229376;

  CArgs ca;
  for (int i = 0; i < 23; ++i) { ca.src[i] = d_in[i]; ca.n[i] = AN[i]; ca.off[i] = AO[i]; }
  kConvert<<<dim3(128, 24), 256, 0, stream>>>(ca, flag, arena,
                                              d_in[19], d_in[20], d_in[21], d_in[17],
                                              Wqk, W2p, Wcb);

  const bf* inputs = arena + AO[0];
  const bf* hidden = arena + AO[1];
  const bf* W1     = arena + AO[3];
  const bf* b1     = arena + AO[4];
  const bf* Wih_c  = arena + AO[5];
  const bf* Whh_c  = arena + AO[6];
  const bf* bih_c  = arena + AO[7];
  const bf* bhh_c  = arena + AO[8];
  const bf* Wih_f  = arena + AO[9];
  const bf* Whh_f  = arena + AO[10];
  const bf* bih_f  = arena + AO[11];
  const bf* bhh_f  = arena + AO[12];
  const bf* Wih_b  = arena + AO[13];
  const bf* Whh_b  = arena + AO[14];
  const bf* bih_b  = arena + AO[15];
  const bf* bhh_b  = arena + AO[16];

  // fused x1 + gi_c + cell GRU (env-local, 1024 blocks)
  kPre<<<dim3(1024), 256, 0, stream>>>(inputs, W1, b1, Wih_c, bih_c, hidden,
                                       Whh_c, bhh_c, hrnn, outh);
  // fused gi-GEMM + 15-step bidirectional GRU -> L (2 dir planes)
  kSeq<<<dim3(1024, 2), 512, 0, stream>>>(hrnn, Wih_f, Wih_b, Whh_f, Whh_b,
                                          bih_f, bih_b, bhh_f, bhh_b, Wcb, L);
  // fused qk + gumbel + attention + out14 GEMM (1024 blocks)
  kTail<<<dim3(1024), 256, 0, stream>>>(hrnn, Wqk, L, d_in[2], d_in[18], flag,
                                        W2p, d_in[22], out14);
}

// Round 8
// 262.595 us; speedup vs baseline: 1.0689x; 1.0077x over previous
//
#include <hip/hip_runtime.h>
#include <hip/hip_bf16.h>

// G2AAgent — ROUND 16: kSeq straggler rotation + C-init extension.
//  R15 post-mortem: (a) C-init -16 adds -> kSeq 119->113.8 (matched);
//  (b) kPre fusion -> non-kSeq UNCHANGED (148->151): per decision rule the
//  non-kSeq floor is fixed overhead + ~40us invisible kernel time. Stop
//  fusing; only in-kernel waste remains. This round:
//   (1) kSeq: logit MFMA rotates across waves (t&7) — wave 0 was doing
//       16 MFMA + 4 LDS + sL stores vs 12 for others EVERY step, then all
//       8 waves barrier on it. lacc has no cross-step state; all waves
//       load the same bh; sWc is LDS. Zero-cost flatten.
//   (2) kSeq: acc[0]=gS[0]+nbR, acc[1]=gS[1]+nbZ at init (add replaces
//       mov+epilogue add, -8 ops/thread-step); gnn hoisted off the
//       post-MFMA dependent chain.
//   (3) kTail: sh staging vectorized (short8, was 8 scalar bf16 loads).
//   (4) kConvert: flag scan 4096->1024 u16 (512 fp32 low-halves: miss
//       prob 0.75^512 ~ 0).
//  absmax: reassociation is ULP-level; rotation exact.

typedef __attribute__((ext_vector_type(8))) short short8;
typedef __attribute__((ext_vector_type(4))) short short4v;
typedef __attribute__((ext_vector_type(4))) float float4v;

#define BF2F(x) __bfloat162float(x)
typedef __hip_bfloat16 bf;

__device__ __forceinline__ float frcp(float x) {
  return __builtin_amdgcn_rcpf(x);
}
__device__ __forceinline__ float fsigmoid(float x) {
  return frcp(1.f + __expf(-x));
}
__device__ __forceinline__ float ftanh(float x) {
  float e = __expf(2.f * x);
  return 1.f - 2.f * frcp(1.f + e);
}
__device__ __forceinline__ float rdv(const void* p, int i, int f) {
  return f ? ((const float*)p)[i] : BF2F(((const bf*)p)[i]);
}

// ---------------------------------------------------------------------------
static const int AO[23] = {
  0, 2097152, 4194304, 4685824, 4702208, 4702336, 4751488, 4800640, 4801024,
  4801408, 4899712, 4948864, 4949248, 4949632, 5047936, 5097088, 5097472,
  5097856, 5098368, 5098384, 5102480, 5106576, 5110160};
static const int AN[23] = {
  2097152, 2097152, 491520, 16384, 128, 49152, 49152, 384, 384, 98304, 49152,
  384, 384, 98304, 49152, 384, 384, 512, 2, 4096, 4096, 3584, 14};

struct CArgs {
  const void* src[23];
  int n[23];
  int off[23];
};

// ---------------------------------------------------------------------------
// kConvert: per-block self-detect of input dtype; y<23 = vectorized
// normalize into arena (skips 2/18/22); y==23 = prep (Wqk/W2p/Wcb).
__global__ void kConvert(CArgs a, int* __restrict__ flagOut,
                         bf* __restrict__ arena,
                         const void* __restrict__ WqR, const void* __restrict__ WkR,
                         const void* __restrict__ W2R, const void* __restrict__ WcR,
                         bf* __restrict__ Wqk, bf* __restrict__ W2p,
                         bf* __restrict__ Wcb) {
  __shared__ int sflag;
  if (threadIdx.x == 0) sflag = 0;
  __syncthreads();
  {
    const unsigned short* p0 = (const unsigned short*)a.src[0];
    int hit = 0;
    for (int i = threadIdx.x; i < 1024; i += 256) {
      int e = (p0[i] >> 7) & 0xFF;
      if (e >= 0xC0) hit = 1;
    }
    if (hit) atomicOr(&sflag, 1);
  }
  __syncthreads();
  const int f = sflag;
  const int b = blockIdx.y;
  if (b == 0 && blockIdx.x == 0 && threadIdx.x == 0) *flagOut = f;

  if (b == 23) {  // prep
    int idx = blockIdx.x * 256 + threadIdx.x;
    if (idx < 8192) {
      int r = idx >> 7, c = idx & 127;
      float v = (r < 32) ? rdv(WqR, r * 128 + c, f) : rdv(WkR, (r - 32) * 128 + c, f);
      Wqk[idx] = __float2bfloat16(v);
    }
    if (idx < 4096)
      W2p[idx] = __float2bfloat16((idx < 3584) ? rdv(W2R, idx, f) : 0.f);
    if (idx < 512) {
      int dir = idx >> 8, l = (idx >> 7) & 1, k = idx & 127;
      Wcb[idx] = __float2bfloat16(rdv(WcR, l * 256 + dir * 128 + k, f));
    }
    return;
  }
  if (b == 2 || b == 18 || b == 22) return;  // consumed raw via rdv
  const int n = a.n[b];
  const int nv = n & ~7;
  bf* dst = arena + a.off[b];
  const int gid = blockIdx.x * 256 + threadIdx.x;
  const int gs = gridDim.x * 256;
  if (f) {
    const float* s = (const float*)a.src[b];
    for (int i = gid * 8; i < nv; i += gs * 8) {
      float4 x0 = *(const float4*)(s + i);
      float4 x1 = *(const float4*)(s + i + 4);
      short8 v;
      bf t;
      t = __float2bfloat16(x0.x); v[0] = *(short*)&t;
      t = __float2bfloat16(x0.y); v[1] = *(short*)&t;
      t = __float2bfloat16(x0.z); v[2] = *(short*)&t;
      t = __float2bfloat16(x0.w); v[3] = *(short*)&t;
      t = __float2bfloat16(x1.x); v[4] = *(short*)&t;
      t = __float2bfloat16(x1.y); v[5] = *(short*)&t;
      t = __float2bfloat16(x1.z); v[6] = *(short*)&t;
      t = __float2bfloat16(x1.w); v[7] = *(short*)&t;
      *(short8*)(dst + i) = v;
    }
    for (int i = nv + gid; i < n; i += gs) dst[i] = __float2bfloat16(s[i]);
  } else {
    const short8* s = (const short8*)a.src[b];
    short8* d = (short8*)dst;
    for (int i = gid; i * 8 < nv; i += gs) d[i] = s[i];
    const unsigned short* ss = (const unsigned short*)a.src[b];
    unsigned short* ds = (unsigned short*)dst;
    for (int i = nv + gid; i < n; i += gs) ds[i] = ss[i];
  }
}

// ---------------------------------------------------------------------------
// kPre: env-local fusion of x1 + gi_c + cell GRU. 1024 blocks x 16 rows.
__global__ __launch_bounds__(256) void kPre(
    const bf* __restrict__ inputs, const bf* __restrict__ W1,
    const bf* __restrict__ b1, const bf* __restrict__ Wih,
    const bf* __restrict__ bih, const bf* __restrict__ hidden,
    const bf* __restrict__ Whh, const bf* __restrict__ bhh,
    bf* __restrict__ hrnn, float* __restrict__ outh) {
  __shared__ bf sX[16][136];  // x1 tile, 4.25 KB
  const int tid = threadIdx.x;
  const int wave = tid >> 6, lane = tid & 63;
  const int quad = lane >> 4, ci = lane & 15;
  const int row0 = blockIdx.x * 16;

  // stage A: swapped -> D[x1col][row]; wave owns col-tiles {2w, 2w+1}.
  float4v xa[2];
#pragma unroll
  for (int i = 0; i < 2; ++i) xa[i] = {0.f, 0.f, 0.f, 0.f};
#pragma unroll
  for (int ks = 0; ks < 4; ++ks) {
    short8 inr = *(const short8*)(inputs + (size_t)(row0 + ci) * 128 + ks * 32 + quad * 8);
#pragma unroll
    for (int c2 = 0; c2 < 2; ++c2) {
      int ct = wave * 2 + c2;
      short8 wfr = *(const short8*)(W1 + (size_t)(ct * 16 + ci) * 128 + ks * 32 + quad * 8);
      xa[c2] = __builtin_amdgcn_mfma_f32_16x16x32_bf16(wfr, inr, xa[c2], 0, 0, 0);
    }
  }
#pragma unroll
  for (int c2 = 0; c2 < 2; ++c2) {
    int ct = wave * 2 + c2;
    short4v v4;
#pragma unroll
    for (int r = 0; r < 4; ++r) {
      float v = xa[c2][r] + BF2F(b1[ct * 16 + quad * 4 + r]);
      v = fmaxf(v, 0.f);
      bf t = __float2bfloat16(v);
      v4[r] = *(short*)&t;
    }
    *(short4v*)&sX[ci][ct * 16 + quad * 4] = v4;
  }
  __syncthreads();

  short8 af[4];
#pragma unroll
  for (int ks = 0; ks < 4; ++ks)
    af[ks] = *(const short8*)&sX[ci][ks * 32 + quad * 8];

  // stage B: gh + gi, standard D[row][col]; wave owns cols wave*32 + nt*16.
  float4v ah[6], ag[6];
#pragma unroll
  for (int i = 0; i < 6; ++i) { ah[i] = {0.f, 0.f, 0.f, 0.f}; ag[i] = {0.f, 0.f, 0.f, 0.f}; }
#pragma unroll
  for (int ks = 0; ks < 4; ++ks) {
    short8 hr = *(const short8*)(hidden + (size_t)(row0 + ci) * 128 + ks * 32 + quad * 8);
#pragma unroll
    for (int g = 0; g < 3; ++g)
#pragma unroll
      for (int nt = 0; nt < 2; ++nt) {
        int wrow = g * 128 + wave * 32 + nt * 16 + ci;
        short8 bw = *(const short8*)(Whh + (size_t)wrow * 128 + ks * 32 + quad * 8);
        ah[g * 2 + nt] = __builtin_amdgcn_mfma_f32_16x16x32_bf16(hr, bw, ah[g * 2 + nt], 0, 0, 0);
        short8 bi_ = *(const short8*)(Wih + (size_t)wrow * 128 + ks * 32 + quad * 8);
        ag[g * 2 + nt] = __builtin_amdgcn_mfma_f32_16x16x32_bf16(af[ks], bi_, ag[g * 2 + nt], 0, 0, 0);
      }
  }

#pragma unroll
  for (int nt = 0; nt < 2; ++nt) {
    int c = wave * 32 + nt * 16 + ci;
    float biR = BF2F(bih[c]),       bhR = BF2F(bhh[c]);
    float biZ = BF2F(bih[128 + c]), bhZ = BF2F(bhh[128 + c]);
    float biN = BF2F(bih[256 + c]), bhN = BF2F(bhh[256 + c]);
#pragma unroll
    for (int r = 0; r < 4; ++r) {
      int rr = row0 + quad * 4 + r;
      float pre_r = ah[nt][r] + (ag[nt][r] + biR) + bhR;
      float pre_z = ah[2 + nt][r] + (ag[2 + nt][r] + biZ) + bhZ;
      float gnn   = ag[4 + nt][r] + biN;
      float hn_   = ah[4 + nt][r] + bhN;
      float rg = fsigmoid(pre_r);
      float zg = fsigmoid(pre_z);
      float ng = ftanh(gnn + rg * hn_);
      float hp = BF2F(hidden[(size_t)rr * 128 + c]);
      float hv = ng + zg * (hp - ng);
      hrnn[(size_t)rr * 128 + c] = __float2bfloat16(hv);
      outh[(size_t)rr * 128 + c] = hv;
    }
  }
}

// ---------------------------------------------------------------------------
// kSeq v9: grid (1024, 2), 512 thr = 8 waves. Operand-swapped MFMAs;
// fp32 nbr-gi; C-init carries gS+nb (r,z) and bNc; logit MFMA ROTATES
// across waves (t&7) to remove the wave-0 straggler.
__global__ __launch_bounds__(512, 4) void kSeq(
    const bf* __restrict__ hrnn,
    const bf* __restrict__ Wih_f, const bf* __restrict__ Wih_b,
    const bf* __restrict__ Whh_f, const bf* __restrict__ Whh_b,
    const bf* __restrict__ bih_f, const bf* __restrict__ bih_b,
    const bf* __restrict__ bhh_f, const bf* __restrict__ bhh_b,
    const bf* __restrict__ Wcb, float* __restrict__ L) {
  __shared__ float sGiN[16][3][132];            // [batch][gate][hcol] fp32 25.3KB
  __shared__ bf sH[2][16][136];                 // h ping-pong [batch][hcol]
  __shared__ float sL[16][15][2];               // logits [batch][m][logit]
  __shared__ bf sWc[2][136];                    // Wc rows for this dir

  const int env = blockIdx.x;
  const int dir = blockIdx.y;
  const int tid = threadIdx.x;
  const int wave = tid >> 6, lane = tid & 63;
  const int nh = wave;
  const int quad = lane >> 4, ci = lane & 15;
  const bf* Wih = dir ? Wih_b : Wih_f;
  const bf* Whh = dir ? Whh_b : Whh_f;
  const bf* bih = dir ? bih_b : bih_f;
  const bf* bhh = dir ? bhh_b : bhh_f;
  const int h0q = nh * 16 + quad * 4;

  // ---- Phase 1: gi GEMM (swapped: D[hcol][batch]) ----
  float4v gS[3], gN[3];
#pragma unroll
  for (int i = 0; i < 3; ++i) { gS[i] = {0.f, 0.f, 0.f, 0.f}; gN[i] = {0.f, 0.f, 0.f, 0.f}; }
#pragma unroll
  for (int ks = 0; ks < 4; ++ks) {
    short8 bh = *(const short8*)(hrnn + (size_t)(env * 16 + ci) * 128 + ks * 32 + quad * 8);
#pragma unroll
    for (int g = 0; g < 3; ++g) {
      const bf* wrow = Wih + (size_t)(g * 128 + nh * 16 + ci) * 256 + ks * 32 + quad * 8;
      short8 ws = *(const short8*)(wrow);
      short8 wn = *(const short8*)(wrow + 128);
      gS[g] = __builtin_amdgcn_mfma_f32_16x16x32_bf16(ws, bh, gS[g], 0, 0, 0);
      gN[g] = __builtin_amdgcn_mfma_f32_16x16x32_bf16(wn, bh, gN[g], 0, 0, 0);
    }
  }
#pragma unroll
  for (int g = 0; g < 3; ++g)
#pragma unroll
    for (int r = 0; r < 4; ++r) {
      int c = g * 128 + h0q + r;
      float bv = BF2F(bih[c]);
      if (g < 2) bv += BF2F(bhh[c]);
      gS[g][r] += bv;
    }
  // nbr-gi straight to LDS as fp32 (one b128 store per gate)
#pragma unroll
  for (int g = 0; g < 3; ++g)
    *(float4v*)&sGiN[ci][g][h0q] = gN[g];

  {
    bf z = __float2bfloat16(0.f);
    bf* p = &sH[0][0][0];
    for (int i = tid; i < 16 * 136; i += 512) p[i] = z;
    if (tid < 256)
      sWc[tid >> 7][tid & 127] = Wcb[(dir * 2 + (tid >> 7)) * 128 + (tid & 127)];
  }

  // ---- Phase 2: persistent Whh A-frags, constants ----
  short8 Bf[12];
#pragma unroll
  for (int g = 0; g < 3; ++g)
#pragma unroll
    for (int ks = 0; ks < 4; ++ks)
      Bf[g * 4 + ks] =
          *(const short8*)(Whh + (size_t)(g * 128 + nh * 16 + ci) * 128 + ks * 32 + quad * 8);

  float4v bNcV;
#pragma unroll
  for (int r = 0; r < 4; ++r) bNcV[r] = BF2F(bhh[256 + h0q + r]);

  float hPrev[4];
#pragma unroll
  for (int r = 0; r < 4; ++r) hPrev[r] = 0.f;

  __syncthreads();

  // ---- Phase 3: 15 steps ----
  for (int t = 0; t < 15; ++t) {
    const int cur = t & 1, nxt = cur ^ 1;
    const int m = dir ? (14 - t) : t;
    const int jr = m + ((m >= ci) ? 1 : 0);
    const int lw = t & 7;                     // logit wave this step

    float4v nbR = *(const float4v*)&sGiN[jr][0][h0q];
    float4v nbZ = *(const float4v*)&sGiN[jr][1][h0q];
    float4v nbN = *(const float4v*)&sGiN[jr][2][h0q];

    // C-init: MFMA chain carries gS+nb (r,z) and bhh_n; gnn hoisted.
    float4v acc[3];
    float gnnV[4];
#pragma unroll
    for (int r = 0; r < 4; ++r) {
      acc[0][r] = gS[0][r] + nbR[r];
      acc[1][r] = gS[1][r] + nbZ[r];
      gnnV[r]   = gS[2][r] + nbN[r];
    }
    acc[2] = bNcV;
    float4v lacc = {0.f, 0.f, 0.f, 0.f};
#pragma unroll
    for (int ks = 0; ks < 4; ++ks) {
      short8 bh = *(const short8*)&sH[cur][ci][ks * 32 + quad * 8];
#pragma unroll
      for (int g = 0; g < 3; ++g)
        acc[g] = __builtin_amdgcn_mfma_f32_16x16x32_bf16(Bf[g * 4 + ks], bh, acc[g], 0, 0, 0);
      if (nh == lw) {
        short8 wv = *(const short8*)&sWc[ci & 1][ks * 32 + quad * 8];
        lacc = __builtin_amdgcn_mfma_f32_16x16x32_bf16(wv, bh, lacc, 0, 0, 0);
      }
    }
    if (nh == lw && t > 0 && quad == 0) {
      int mp = dir ? (15 - t) : (t - 1);
      sL[ci][mp][0] = lacc[0];
      sL[ci][mp][1] = lacc[1];
    }

    short4v hv4;
#pragma unroll
    for (int r = 0; r < 4; ++r) {
      float pre_r = acc[0][r];
      float pre_z = acc[1][r];
      float hn_   = acc[2][r];
      float rg = fsigmoid(pre_r);
      float zg = fsigmoid(pre_z);
      float ng = ftanh(gnnV[r] + rg * hn_);
      float hv = ng + zg * (hPrev[r] - ng);
      hPrev[r] = hv;
      bf b = __float2bfloat16(hv);
      hv4[r] = *(short*)&b;
    }
    *(short4v*)&sH[nxt][ci][h0q] = hv4;
    __syncthreads();
  }

  if (nh == 0) {
    float4v lacc = {0.f, 0.f, 0.f, 0.f};
#pragma unroll
    for (int ks = 0; ks < 4; ++ks) {
      short8 bh = *(const short8*)&sH[1][ci][ks * 32 + quad * 8];
      short8 wv = *(const short8*)&sWc[ci & 1][ks * 32 + quad * 8];
      lacc = __builtin_amdgcn_mfma_f32_16x16x32_bf16(wv, bh, lacc, 0, 0, 0);
    }
    if (quad == 0) {
      int mf = dir ? 0 : 14;
      sL[ci][mf][0] = lacc[0];
      sL[ci][mf][1] = lacc[1];
    }
  }
  __syncthreads();

  {
    float* Ld = L + (size_t)dir * 491520 + (size_t)env * 480;
    for (int i = tid; i < 480; i += 512) {
      int row = i / 30, rem = i - row * 30;
      int mm = rem >> 1, l = rem & 1;
      Ld[i] = sL[row][mm][l];
    }
  }
}

// ---------------------------------------------------------------------------
// kTail: 1024 blocks x 1 env. qk MFMA + gumbel + attn -> sAgg (LDS),
// then out14 GEMM (wave 0) for this env's 16 rows.
__global__ __launch_bounds__(256) void kTail(
    const bf* __restrict__ h, const bf* __restrict__ Wqk,
    const float* __restrict__ L, const void* __restrict__ guRaw,
    const void* __restrict__ bcRaw, const int* __restrict__ flag,
    const bf* __restrict__ W2p, const void* __restrict__ b2Raw,
    float* __restrict__ out) {
  __shared__ float sh[16 * 132];
  __shared__ float sqk[16 * 64];
  __shared__ float shw[240];
  __shared__ float sw[16 * 16];
  __shared__ bf sAgg[16][136];
  const int bb = blockIdx.x;
  const int tid = threadIdx.x;
  const int f = *flag;
  const int a = tid >> 4, i = tid & 15;

  {
    const int w = tid >> 6, lane = tid & 63;
    const int quad = lane >> 4, ci = lane & 15;
    float4v acc = {0.f, 0.f, 0.f, 0.f};
#pragma unroll
    for (int ks = 0; ks < 4; ++ks) {
      short8 a_ = *(const short8*)(h + (size_t)(bb * 16 + ci) * 128 + ks * 32 + quad * 8);
      short8 b_ = *(const short8*)(Wqk + (size_t)(w * 16 + ci) * 128 + ks * 32 + quad * 8);
      acc = __builtin_amdgcn_mfma_f32_16x16x32_bf16(a_, b_, acc, 0, 0, 0);
    }
#pragma unroll
    for (int r = 0; r < 4; ++r)
      sqk[(quad * 4 + r) * 64 + w * 16 + ci] = acc[r];
  }
  {
    // vectorized h staging: one short8 per thread (row = tid>>4, col = (tid&15)*8)
    short8 hv = *(const short8*)(h + (size_t)bb * 2048 + tid * 8);
    int row = tid >> 4, col = (tid & 15) * 8;
    float* dst = &sh[row * 132 + col];
#pragma unroll
    for (int d = 0; d < 8; ++d) {
      unsigned short u = (unsigned short)hv[d];
      dst[d] = BF2F(*(const bf*)&u);
    }
  }
  if (tid < 240) {
    int idx = bb * 240 + tid;
    float l0 = L[(size_t)idx * 2]     + L[491520 + (size_t)idx * 2]     + rdv(bcRaw, 0, f);
    float l1 = L[(size_t)idx * 2 + 1] + L[491520 + (size_t)idx * 2 + 1] + rdv(bcRaw, 1, f);
    float u0 = rdv(guRaw, idx * 2, f);
    float u1 = rdv(guRaw, idx * 2 + 1, f);
    float g0 = -__logf(-__logf(u0 + 1e-10f) + 1e-10f);
    float g1 = -__logf(-__logf(u1 + 1e-10f) + 1e-10f);
    shw[tid] = fsigmoid(((l1 + g1) - (l0 + g0)) * 2.0f);
  }
  __syncthreads();

  float s = -1e30f;
  if (i < 15) {
    int j = i + (i >= a);
    float d = 0.f;
#pragma unroll
    for (int c = 0; c < 32; ++c) d += sqk[a * 64 + c] * sqk[j * 64 + 32 + c];
    s = shw[a * 15 + i] * d * 0.17677669529663687f;
  }
  float mx = s;
#pragma unroll
  for (int d = 1; d < 16; d <<= 1) mx = fmaxf(mx, __shfl_xor(mx, d));
  float ex = (i < 15) ? __expf(s - mx) : 0.f;
  float sum = ex;
#pragma unroll
  for (int d = 1; d < 16; d <<= 1) sum += __shfl_xor(sum, d);
  float w = (i < 15) ? (ex * frcp(sum)) * shw[a * 15 + i] : 0.f;
  sw[a * 16 + i] = w;
  __syncthreads();

  float ac[8] = {0, 0, 0, 0, 0, 0, 0, 0};
  for (int mm = 0; mm < 15; ++mm) {
    int jm = mm + (mm >= a);
    float wm = sw[a * 16 + mm];
    const float* shp = &sh[jm * 132 + i * 8];
    float4 h0 = *(const float4*)shp;
    float4 h1 = *(const float4*)(shp + 4);
    ac[0] += wm * h0.x; ac[1] += wm * h0.y; ac[2] += wm * h0.z; ac[3] += wm * h0.w;
    ac[4] += wm * h1.x; ac[5] += wm * h1.y; ac[6] += wm * h1.z; ac[7] += wm * h1.w;
  }
  short8 v;
#pragma unroll
  for (int d = 0; d < 8; ++d) {
    bf b = __float2bfloat16(ac[d]);
    v[d] = *(short*)&b;
  }
  *(short8*)&sAgg[a][i * 8] = v;
  __syncthreads();

  // out14 GEMM for this env's 16 rows (wave 0)
  if (tid < 64) {
    const int quad = tid >> 4, ci = tid & 15;
    const int mr = bb * 16;
    float4v acc = {0.f, 0.f, 0.f, 0.f};
#pragma unroll
    for (int ks = 0; ks < 4; ++ks) {
      short8 a_ = *(const short8*)(h + (size_t)(mr + ci) * 128 + ks * 32 + quad * 8);
      short8 b_ = *(const short8*)(W2p + (size_t)ci * 256 + ks * 32 + quad * 8);
      acc = __builtin_amdgcn_mfma_f32_16x16x32_bf16(a_, b_, acc, 0, 0, 0);
    }
#pragma unroll
    for (int ks = 0; ks < 4; ++ks) {
      short8 a_ = *(const short8*)&sAgg[ci][ks * 32 + quad * 8];
      short8 b_ = *(const short8*)(W2p + (size_t)ci * 256 + 128 + ks * 32 + quad * 8);
      acc = __builtin_amdgcn_mfma_f32_16x16x32_bf16(a_, b_, acc, 0, 0, 0);
    }
    if (ci < 14) {
      float bv = rdv(b2Raw, ci, f);
#pragma unroll
      for (int r = 0; r < 4; ++r)
        out[(size_t)(mr + quad * 4 + r) * 14 + ci] = acc[r] + bv;
    }
  }
}

// ---------------------------------------------------------------------------
extern "C" void kernel_launch(void* const* d_in, const int* in_sizes, int n_in,
                              void* d_out, int out_size, void* d_ws, size_t ws_size,
                              hipStream_t stream) {
  const size_t OFF_ARENA = 0;          // bf16 arena; L (3.93MB) overlaps dead
                                       //   inputs+hidden [0, 8.38MB) after kPre
  const size_t OFF_FLAG  = 10220544;
  const size_t OFF_WQK   = 26998016;   // 16 KB
  const size_t OFF_WCB   = 27014400;   // 1 KB
  const size_t OFF_W2P   = 27410944;   // 8 KB
  const size_t OFF_HRNN  = 27419136;   // 4 MB
  const size_t NEEDED    = 84042240;
  if (ws_size < NEEDED) return;
  if (n_in < 23 || in_sizes[0] != 2097152 || in_sizes[3] != 16384 ||
      in_sizes[5] != 49152 || in_sizes[9] != 98304 || in_sizes[17] != 512 ||
      in_sizes[19] != 4096 || in_sizes[21] != 3584 || out_size != 2326528)
    return;

  char* ws = (char*)d_ws;
  bf*    arena = (bf*)(ws + OFF_ARENA);
  float* L     = (float*)(ws + OFF_ARENA);  // 3.93 MB; valid after kPre
  int*   flag  = (int*)(ws + OFF_FLAG);
  bf*    Wqk   = (bf*)(ws + OFF_WQK);
  bf*    Wcb   = (bf*)(ws + OFF_WCB);
  bf*    W2p   = (bf*)(ws + OFF_W2P);
  bf*    hrnn  = (bf*)(ws + OFF_HRNN);

  float* out14 = (float*)d_out;
  float* outh  = (float*)d_out + 229376;

  CArgs ca;
  for (int i = 0; i < 23; ++i) { ca.src[i] = d_in[i]; ca.n[i] = AN[i]; ca.off[i] = AO[i]; }
  kConvert<<<dim3(128, 24), 256, 0, stream>>>(ca, flag, arena,
                                              d_in[19], d_in[20], d_in[21], d_in[17],
                                              Wqk, W2p, Wcb);

  const bf* inputs = arena + AO[0];
  const bf* hidden = arena + AO[1];
  const bf* W1     = arena + AO[3];
  const bf* b1     = arena + AO[4];
  const bf* Wih_c  = arena + AO[5];
  const bf* Whh_c  = arena + AO[6];
  const bf* bih_c  = arena + AO[7];
  const bf* bhh_c  = arena + AO[8];
  const bf* Wih_f  = arena + AO[9];
  const bf* Whh_f  = arena + AO[10];
  const bf* bih_f  = arena + AO[11];
  const bf* bhh_f  = arena + AO[12];
  const bf* Wih_b  = arena + AO[13];
  const bf* Whh_b  = arena + AO[14];
  const bf* bih_b  = arena + AO[15];
  const bf* bhh_b  = arena + AO[16];

  // fused x1 + gi_c + cell GRU (env-local, 1024 blocks)
  kPre<<<dim3(1024), 256, 0, stream>>>(inputs, W1, b1, Wih_c, bih_c, hidden,
                                       Whh_c, bhh_c, hrnn, outh);
  // fused gi-GEMM + 15-step bidirectional GRU -> L (2 dir planes)
  kSeq<<<dim3(1024, 2), 512, 0, stream>>>(hrnn, Wih_f, Wih_b, Whh_f, Whh_b,
                                          bih_f, bih_b, bhh_f, bhh_b, Wcb, L);
  // fused qk + gumbel + attention + out14 GEMM (1024 blocks)
  kTail<<<dim3(1024), 256, 0, stream>>>(hrnn, Wqk, L, d_in[2], d_in[18], flag,
                                        W2p, d_in[22], out14);
}